// Round 1
// baseline (1952.600 us; speedup 1.0000x reference)
//
#include <hip/hip_runtime.h>
#include <math.h>

// LinformerAttention on MI355X — Round 1: correct fp32 vector implementation.
// B=8 T=2048 C=1024 H=16 D=64 Kproj=128.
// ws layout: [qkv: M*3C floats][kproj: B*H*KP*D][vproj: B*H*KP*D]
// y is written into the (dead after proj_kv) v-columns of qkv (offset 2C, ld 3C).

constexpr int B_ = 8, T_ = 2048, C_ = 1024, H_ = 16, D_ = 64, KP = 128;
constexpr int M_ = B_ * T_;            // 16384
constexpr int C3 = 3 * C_;             // 3072

// ---------------------------------------------------------------------------
// Generic tiled SGEMM: C = A(MxK) * B(KxN) + bias, row-major with strides.
// 128x128 tile, BK=16, 256 threads, 8x8 accumulators (split 4+4 per dim for
// conflict-free LDS float4 reads).
// ---------------------------------------------------------------------------
__global__ __launch_bounds__(256) void sgemm_bias(
    const float* __restrict__ A, const float* __restrict__ Bm,
    const float* __restrict__ bias, float* __restrict__ Cm,
    int M, int N, int K, int lda, int ldb, int ldc)
{
  constexpr int BM = 128, BN = 128, BK = 16;
  __shared__ float As[BK][BM + 4];   // transposed [k][m]; pitch 132 (16B aligned)
  __shared__ float Bs[BK][BN];
  const int tid = threadIdx.x;
  const int tx = tid & 15;           // col group
  const int ty = tid >> 4;           // row group
  const int m0 = blockIdx.y * BM;
  const int n0 = blockIdx.x * BN;

  const int arow = tid >> 2;         // 0..63 (+64 for l=1)
  const int acol = (tid & 3) << 2;   // 0,4,8,12
  const int brow = tid >> 5;         // 0..7 (+8 for l=1)
  const int bcol = (tid & 31) << 2;  // 0..124

  float acc[8][8];
  #pragma unroll
  for (int i = 0; i < 8; ++i)
    #pragma unroll
    for (int j = 0; j < 8; ++j) acc[i][j] = 0.f;

  for (int k0 = 0; k0 < K; k0 += BK) {
    #pragma unroll
    for (int l = 0; l < 2; ++l) {
      const float4 av = *reinterpret_cast<const float4*>(
          &A[(size_t)(m0 + arow + l * 64) * lda + k0 + acol]);
      As[acol + 0][arow + l * 64] = av.x;
      As[acol + 1][arow + l * 64] = av.y;
      As[acol + 2][arow + l * 64] = av.z;
      As[acol + 3][arow + l * 64] = av.w;
    }
    #pragma unroll
    for (int l = 0; l < 2; ++l) {
      *reinterpret_cast<float4*>(&Bs[brow + l * 8][bcol]) =
          *reinterpret_cast<const float4*>(
              &Bm[(size_t)(k0 + brow + l * 8) * ldb + n0 + bcol]);
    }
    __syncthreads();
    #pragma unroll
    for (int kk = 0; kk < BK; ++kk) {
      float a[8], b[8];
      #pragma unroll
      for (int i = 0; i < 4; ++i) {
        a[i]     = As[kk][ty * 4 + i];
        a[4 + i] = As[kk][64 + ty * 4 + i];
      }
      #pragma unroll
      for (int j = 0; j < 4; ++j) {
        b[j]     = Bs[kk][tx * 4 + j];
        b[4 + j] = Bs[kk][64 + tx * 4 + j];
      }
      #pragma unroll
      for (int i = 0; i < 8; ++i)
        #pragma unroll
        for (int j = 0; j < 8; ++j)
          acc[i][j] += a[i] * b[j];
    }
    __syncthreads();
  }
  #pragma unroll
  for (int i = 0; i < 8; ++i) {
    const int m = m0 + ((i < 4) ? (ty * 4 + i) : (64 + ty * 4 + i - 4));
    #pragma unroll
    for (int jh = 0; jh < 2; ++jh) {
      const int n = n0 + jh * 64 + tx * 4;
      float4 o;
      o.x = acc[i][jh * 4 + 0] + bias[n + 0];
      o.y = acc[i][jh * 4 + 1] + bias[n + 1];
      o.z = acc[i][jh * 4 + 2] + bias[n + 2];
      o.w = acc[i][jh * 4 + 3] + bias[n + 3];
      *reinterpret_cast<float4*>(&Cm[(size_t)m * ldc + n]) = o;
    }
  }
}

// ---------------------------------------------------------------------------
// k_proj[b,h] = E_h(128x2048) @ K_bh(2048x64); v_proj with F/v.
// grid (B*H, 2): y==0 -> E/k, y==1 -> F/v. 256 threads, 8x4 accs/thread.
// ---------------------------------------------------------------------------
__global__ __launch_bounds__(256) void proj_kv(
    const float* __restrict__ qkv, const float* __restrict__ E,
    const float* __restrict__ F, float* __restrict__ kproj,
    float* __restrict__ vproj)
{
  const int bh = blockIdx.x;
  const int b = bh >> 4;
  const int h = bh & 15;
  const bool isV = (blockIdx.y == 1);
  const float* Emat = (isV ? F : E) + (size_t)h * KP * T_;
  const float* Kg = qkv + (size_t)b * T_ * C3 + (isV ? 2 * C_ : C_) + h * D_;
  float* outp = (isV ? vproj : kproj) + (size_t)bh * KP * D_;

  __shared__ float Es[16][KP + 1];   // transposed [t][kk]
  __shared__ float Ks[16][D_];       // [t][d]
  const int tid = threadIdx.x;
  const int cg = tid & 15;           // d group (4 each)
  const int rg = tid >> 4;           // kk group (4+4, 64 apart)

  const int ekk = tid >> 2;          // 0..63 (+64)
  const int etc = (tid & 3) << 2;    // t chunk
  const int ktl = tid >> 4;          // 0..15
  const int kdc = (tid & 15) << 2;   // 0..60

  float acc[8][4];
  #pragma unroll
  for (int i = 0; i < 8; ++i)
    #pragma unroll
    for (int j = 0; j < 4; ++j) acc[i][j] = 0.f;

  for (int t0 = 0; t0 < T_; t0 += 16) {
    #pragma unroll
    for (int l = 0; l < 2; ++l) {
      const float4 ev = *reinterpret_cast<const float4*>(
          &Emat[(size_t)(ekk + l * 64) * T_ + t0 + etc]);
      Es[etc + 0][ekk + l * 64] = ev.x;
      Es[etc + 1][ekk + l * 64] = ev.y;
      Es[etc + 2][ekk + l * 64] = ev.z;
      Es[etc + 3][ekk + l * 64] = ev.w;
    }
    *reinterpret_cast<float4*>(&Ks[ktl][kdc]) =
        *reinterpret_cast<const float4*>(&Kg[(size_t)(t0 + ktl) * C3 + kdc]);
    __syncthreads();
    #pragma unroll
    for (int tt = 0; tt < 16; ++tt) {
      float e[8], kv[4];
      #pragma unroll
      for (int i = 0; i < 4; ++i) {
        e[i]     = Es[tt][rg * 4 + i];
        e[4 + i] = Es[tt][64 + rg * 4 + i];
      }
      #pragma unroll
      for (int j = 0; j < 4; ++j) kv[j] = Ks[tt][cg * 4 + j];
      #pragma unroll
      for (int i = 0; i < 8; ++i)
        #pragma unroll
        for (int j = 0; j < 4; ++j)
          acc[i][j] += e[i] * kv[j];
    }
    __syncthreads();
  }
  #pragma unroll
  for (int i = 0; i < 8; ++i) {
    const int kk = (i < 4) ? (rg * 4 + i) : (64 + rg * 4 + i - 4);
    const float4 o = make_float4(acc[i][0], acc[i][1], acc[i][2], acc[i][3]);
    *reinterpret_cast<float4*>(&outp[kk * D_ + cg * 4]) = o;
  }
}

// ---------------------------------------------------------------------------
// Attention core: per (b,h, 32-row t-tile):
//   logits = q @ k_proj^T * 0.125 -> softmax -> y = att @ v_proj
// KVs buffer holds k_proj for phase A, reused for v_proj in phase C.
// y written into the v-columns of qkv (caller passes qkv + 2C, ld = 3C).
// ---------------------------------------------------------------------------
__global__ __launch_bounds__(256) void attn_core(
    const float* __restrict__ qkv, const float* __restrict__ kproj,
    const float* __restrict__ vproj, float* __restrict__ y)
{
  constexpr int TT = 32;
  constexpr int PITCH = 68;          // 68%32=4 -> conflict-free phase-A reads
  const int nchunk = T_ / TT;        // 64
  const int blk = blockIdx.x;
  const int bh = blk / nchunk;
  const int tch = blk % nchunk;
  const int b = bh >> 4, h = bh & 15;
  const int t0 = tch * TT;

  __shared__ float KVs[KP][PITCH];   // 34.0 KB
  __shared__ float qs[TT][PITCH];    //  8.5 KB
  __shared__ float att[TT][KP + 1];  // 16.1 KB  (total < 60 KB)

  const int tid = threadIdx.x;

  { // load q tile (32 x 64): 2 float4 / thread
    const float* qg = qkv + (size_t)(b * T_ + t0) * C3 + h * D_;
    #pragma unroll
    for (int l = 0; l < 2; ++l) {
      const int idx = tid + l * 256;
      const int tl = idx >> 4;
      const int dc = (idx & 15) << 2;
      *reinterpret_cast<float4*>(&qs[tl][dc]) =
          *reinterpret_cast<const float4*>(&qg[(size_t)tl * C3 + dc]);
    }
  }
  { // load k_proj (128 x 64): 8 float4 / thread
    const float* kp = kproj + (size_t)bh * KP * D_;
    #pragma unroll
    for (int l = 0; l < 8; ++l) {
      const int idx = tid + l * 256;
      const int kk = idx >> 4;
      const int dc = (idx & 15) << 2;
      *reinterpret_cast<float4*>(&KVs[kk][dc]) =
          *reinterpret_cast<const float4*>(&kp[(size_t)kk * D_ + dc]);
    }
  }
  __syncthreads();

  // phase A: thread owns rows rowg*4+{0..3}, kk = kset + 32*{0..3}
  const int kset = tid & 31;
  const int rowg = tid >> 5;
  float lg[4][4];
  #pragma unroll
  for (int i = 0; i < 4; ++i)
    #pragma unroll
    for (int j = 0; j < 4; ++j) lg[i][j] = 0.f;

  for (int d0 = 0; d0 < D_; d0 += 4) {
    float4 q4[4], k4[4];
    #pragma unroll
    for (int i = 0; i < 4; ++i)
      q4[i] = *reinterpret_cast<const float4*>(&qs[rowg * 4 + i][d0]);
    #pragma unroll
    for (int j = 0; j < 4; ++j)
      k4[j] = *reinterpret_cast<const float4*>(&KVs[kset + 32 * j][d0]);
    #pragma unroll
    for (int i = 0; i < 4; ++i)
      #pragma unroll
      for (int j = 0; j < 4; ++j)
        lg[i][j] += q4[i].x * k4[j].x + q4[i].y * k4[j].y +
                    q4[i].z * k4[j].z + q4[i].w * k4[j].w;
  }

  // phase B: softmax per row across the 32 lanes (kset) of this rowg
  const float scale = 0.125f;        // 1/sqrt(64)
  #pragma unroll
  for (int i = 0; i < 4; ++i) {
    float mx = -1e30f;
    #pragma unroll
    for (int j = 0; j < 4; ++j) { lg[i][j] *= scale; mx = fmaxf(mx, lg[i][j]); }
    #pragma unroll
    for (int s = 16; s >= 1; s >>= 1) mx = fmaxf(mx, __shfl_xor(mx, s, 64));
    float e[4], sum = 0.f;
    #pragma unroll
    for (int j = 0; j < 4; ++j) { e[j] = __expf(lg[i][j] - mx); sum += e[j]; }
    #pragma unroll
    for (int s = 16; s >= 1; s >>= 1) sum += __shfl_xor(sum, s, 64);
    const float inv = 1.f / sum;
    #pragma unroll
    for (int j = 0; j < 4; ++j) att[rowg * 4 + i][kset + 32 * j] = e[j] * inv;
  }
  __syncthreads();

  { // load v_proj over KVs
    const float* vp = vproj + (size_t)bh * KP * D_;
    #pragma unroll
    for (int l = 0; l < 8; ++l) {
      const int idx = tid + l * 256;
      const int kk = idx >> 4;
      const int dc = (idx & 15) << 2;
      *reinterpret_cast<float4*>(&KVs[kk][dc]) =
          *reinterpret_cast<const float4*>(&vp[(size_t)kk * D_ + dc]);
    }
  }
  __syncthreads();

  // phase C: thread owns rows rowg2*2+{0,1}, d = dg*4..+3
  const int dg = tid & 15;
  const int rowg2 = tid >> 4;
  float yacc[2][4];
  #pragma unroll
  for (int i = 0; i < 2; ++i)
    #pragma unroll
    for (int j = 0; j < 4; ++j) yacc[i][j] = 0.f;

  for (int kk = 0; kk < KP; ++kk) {
    const float w0 = att[rowg2 * 2 + 0][kk];
    const float w1 = att[rowg2 * 2 + 1][kk];
    const float4 v4 = *reinterpret_cast<const float4*>(&KVs[kk][dg * 4]);
    yacc[0][0] += w0 * v4.x; yacc[0][1] += w0 * v4.y;
    yacc[0][2] += w0 * v4.z; yacc[0][3] += w0 * v4.w;
    yacc[1][0] += w1 * v4.x; yacc[1][1] += w1 * v4.y;
    yacc[1][2] += w1 * v4.z; yacc[1][3] += w1 * v4.w;
  }
  #pragma unroll
  for (int i = 0; i < 2; ++i) {
    const int t = t0 + rowg2 * 2 + i;
    const float4 o = make_float4(yacc[i][0], yacc[i][1], yacc[i][2], yacc[i][3]);
    *reinterpret_cast<float4*>(&y[(size_t)(b * T_ + t) * C3 + h * D_ + dg * 4]) = o;
  }
}

// ---------------------------------------------------------------------------
extern "C" void kernel_launch(void* const* d_in, const int* in_sizes, int n_in,
                              void* d_out, int out_size, void* d_ws, size_t ws_size,
                              hipStream_t stream) {
  (void)in_sizes; (void)n_in; (void)out_size; (void)ws_size;
  const float* x      = (const float*)d_in[0];
  const float* W_attn = (const float*)d_in[1];
  const float* b_attn = (const float*)d_in[2];
  const float* W_proj = (const float*)d_in[3];
  const float* b_proj = (const float*)d_in[4];
  const float* E      = (const float*)d_in[5];
  const float* F      = (const float*)d_in[6];
  float* out = (float*)d_out;
  float* ws  = (float*)d_ws;

  float* qkv   = ws;                                   // 16384*3072 = 192 MB
  float* kproj = ws + (size_t)M_ * C3;                 // 4 MB
  float* vproj = kproj + (size_t)B_ * H_ * KP * D_;    // 4 MB
  float* y     = qkv + 2 * C_;                         // reuse dead v-columns, ld=3C

  // 1) qkv = x @ W_attn + b_attn         (103 GF)
  sgemm_bias<<<dim3(C3 / 128, M_ / 128), 256, 0, stream>>>(
      x, W_attn, b_attn, qkv, M_, C3, C_, C_, C3, C3);
  // 2) k_proj = E@k, v_proj = F@v        (17 GF)
  proj_kv<<<dim3(B_ * H_, 2), 256, 0, stream>>>(qkv, E, F, kproj, vproj);
  // 3) att + softmax + att@v_proj -> y   (17 GF)
  attn_core<<<dim3(B_ * H_ * (T_ / 32)), 256, 0, stream>>>(qkv, kproj, vproj, y);
  // 4) out = y @ W_proj + b_proj         (34 GF)
  sgemm_bias<<<dim3(C_ / 128, M_ / 128), 256, 0, stream>>>(
      y, W_proj, b_proj, out, M_, C_, C_, C3, C_, C_);
}

// Round 3
// 904.390 us; speedup vs baseline: 2.1590x; 2.1590x over previous
//
#include <hip/hip_runtime.h>
#include <math.h>

// LinformerAttention on MI355X — Round 3: split-bf16 MFMA GEMMs with staged
// buffer lifetimes to keep ws peak at 182 MB (Round 2's 284 MB crashed —
// suspected ws overflow). GEMM1 split into k/v/q GEMMs sharing one region.
// B=8 T=2048 C=1024 H=16 D=64 Kproj=128.

constexpr int B_ = 8, T_ = 2048, C_ = 1024, H_ = 16, D_ = 64, KP = 128;
constexpr int M_ = B_ * T_;            // 16384
constexpr int C3 = 3 * C_;             // 3072
constexpr int K_ = C_;                 // GEMM K = 1024 for all MFMA GEMMs
constexpr int TCH = 8;                 // proj T-chunks (parallelism)

typedef __attribute__((ext_vector_type(8))) short bf16x8;   // 8 bf16 = 4 VGPR
typedef __attribute__((ext_vector_type(4))) float f32x4;

__device__ __forceinline__ unsigned short f2bf(float f) {
  unsigned u = __builtin_bit_cast(unsigned, f);
  u += 0x7FFFu + ((u >> 16) & 1u);     // round-to-nearest-even
  return (unsigned short)(u >> 16);
}
__device__ __forceinline__ float bf2f(unsigned short h) {
  unsigned u = ((unsigned)h) << 16;
  return __builtin_bit_cast(float, u);
}

#define GLOAD_LDS16(gptr, lptr)                                                \
  __builtin_amdgcn_global_load_lds(                                            \
      (const __attribute__((address_space(1))) void*)(gptr),                   \
      (__attribute__((address_space(3))) void*)(lptr), 16, 0, 0)

// ---------------------------------------------------------------------------
// Split fp32 row-major array into hi/lo bf16 (same layout). n4 = n/4.
// ---------------------------------------------------------------------------
__global__ __launch_bounds__(256) void split_rm(
    const float* __restrict__ in, unsigned short* __restrict__ hi,
    unsigned short* __restrict__ lo, int n4)
{
  int i = blockIdx.x * 256 + threadIdx.x;
  if (i >= n4) return;
  const float4 v = reinterpret_cast<const float4*>(in)[i];
  ushort4 h, l;
  h.x = f2bf(v.x); l.x = f2bf(v.x - bf2f(h.x));
  h.y = f2bf(v.y); l.y = f2bf(v.y - bf2f(h.y));
  h.z = f2bf(v.z); l.z = f2bf(v.z - bf2f(h.z));
  h.w = f2bf(v.w); l.w = f2bf(v.w - bf2f(h.w));
  reinterpret_cast<ushort4*>(hi)[i] = h;
  reinterpret_cast<ushort4*>(lo)[i] = l;
}

// ---------------------------------------------------------------------------
// Transpose + split: W [rows][cols] fp32 -> Thi/Tlo [cols][rows] bf16.
// Tlo may be null. 32x32 LDS tile.
// ---------------------------------------------------------------------------
__global__ __launch_bounds__(256) void split_tr(
    const float* __restrict__ W, unsigned short* __restrict__ Thi,
    unsigned short* __restrict__ Tlo, int rows, int cols)
{
  __shared__ float tile[32][33];
  const int c0 = blockIdx.x * 32, r0 = blockIdx.y * 32;
  const int tx = threadIdx.x & 31, ty = threadIdx.x >> 5;   // ty 0..7
  #pragma unroll
  for (int i = 0; i < 4; ++i)
    tile[ty + i * 8][tx] = W[(size_t)(r0 + ty + i * 8) * cols + c0 + tx];
  __syncthreads();
  #pragma unroll
  for (int i = 0; i < 4; ++i) {
    const int cr = ty + i * 8;
    const float v = tile[tx][cr];                 // = W[r0+tx][c0+cr]
    const size_t o = (size_t)(c0 + cr) * rows + r0 + tx;
    const unsigned short h = f2bf(v);
    Thi[o] = h;
    if (Tlo) Tlo[o] = f2bf(v - bf2f(h));
  }
}

// ---------------------------------------------------------------------------
// Split-bf16 MFMA GEMM: C(fp32, 16384xN) = (Ahi+Alo)(MxK) * B(KxN) + bias.
// B given TRANSPOSED: BThi/BTlo are [N][K] bf16, K=1024.
// NPROD==3: Ahi*Bhi + Ahi*Blo + Alo*Bhi.  NPROD==2: Ahi*Bhi + Alo*Bhi.
// 256 thr = 4 waves, wave = 64x64 (4x4 tiles of 16x16x32 MFMA).
// LDS via global_load_lds(16B): wave-uniform base + lane*16, no padding.
// ---------------------------------------------------------------------------
template <int NPROD>
__global__ __launch_bounds__(256) void gemm_mfma_split(
    const unsigned short* __restrict__ Ahi, const unsigned short* __restrict__ Alo,
    const unsigned short* __restrict__ BThi, const unsigned short* __restrict__ BTlo,
    const float* __restrict__ bias, float* __restrict__ Cm, int ldc)
{
  constexpr int NBUF = (NPROD == 3) ? 4 : 3;
  __shared__ unsigned short lds[NBUF * 4096];      // 4096 bf16 = 128x32 per buf
  unsigned short* sAhi = lds;
  unsigned short* sAlo = lds + 4096;
  unsigned short* sBhi = lds + 8192;
  unsigned short* sBlo = lds + 12288;              // only touched if NPROD==3

  const int tid  = threadIdx.x;
  const int lane = tid & 63;
  const int wid  = tid >> 6;
  const int m0 = blockIdx.y * 128;
  const int n0 = blockIdx.x * 128;

  const int srow  = lane >> 2;                     // staging row within 16-chunk
  const int skseg = (lane & 3) << 3;               // staging k sub-offset (8 bf16)
  const int col  = lane & 15;
  const int quad = lane >> 4;
  const int Rm = (wid >> 1) << 6;
  const int Rn = (wid & 1) << 6;

  f32x4 acc[4][4];
  #pragma unroll
  for (int i = 0; i < 4; ++i)
    #pragma unroll
    for (int j = 0; j < 4; ++j)
      acc[i][j] = (f32x4){0.f, 0.f, 0.f, 0.f};

  for (int k0 = 0; k0 < K_; k0 += 32) {
    #pragma unroll
    for (int r = 0; r < 2; ++r) {
      const int chunk = (r << 2) + wid;            // 0..7, wave-uniform
      const int row = (chunk << 4) + srow;         // 0..127 per-lane
      const int ldso = chunk << 9;                 // 512 bf16 per chunk
      const size_t ga = (size_t)(m0 + row) * K_ + k0 + skseg;
      const size_t gb = (size_t)(n0 + row) * K_ + k0 + skseg;
      GLOAD_LDS16(Ahi + ga, sAhi + ldso);
      GLOAD_LDS16(Alo + ga, sAlo + ldso);
      GLOAD_LDS16(BThi + gb, sBhi + ldso);
      if constexpr (NPROD == 3) GLOAD_LDS16(BTlo + gb, sBlo + ldso);
    }
    __syncthreads();

    bf16x8 ah[4], al[4], bh[4], bl[4];
    #pragma unroll
    for (int t = 0; t < 4; ++t) {
      const int ao = ((Rm + (t << 4) + col) << 5) + (quad << 3);
      ah[t] = *reinterpret_cast<const bf16x8*>(sAhi + ao);
      al[t] = *reinterpret_cast<const bf16x8*>(sAlo + ao);
      const int bo = ((Rn + (t << 4) + col) << 5) + (quad << 3);
      bh[t] = *reinterpret_cast<const bf16x8*>(sBhi + bo);
      if constexpr (NPROD == 3)
        bl[t] = *reinterpret_cast<const bf16x8*>(sBlo + bo);
    }
    #pragma unroll
    for (int i = 0; i < 4; ++i)
      #pragma unroll
      for (int j = 0; j < 4; ++j) {
        acc[i][j] = __builtin_amdgcn_mfma_f32_16x16x32_bf16(ah[i], bh[j], acc[i][j], 0, 0, 0);
        acc[i][j] = __builtin_amdgcn_mfma_f32_16x16x32_bf16(al[i], bh[j], acc[i][j], 0, 0, 0);
        if constexpr (NPROD == 3)
          acc[i][j] = __builtin_amdgcn_mfma_f32_16x16x32_bf16(ah[i], bl[j], acc[i][j], 0, 0, 0);
      }
    __syncthreads();
  }

  // Epilogue: C/D layout col=lane&15, row=quad*4+reg (verified m89/m91).
  #pragma unroll
  for (int i = 0; i < 4; ++i) {
    const int rbase = m0 + Rm + (i << 4) + (quad << 2);
    #pragma unroll
    for (int j = 0; j < 4; ++j) {
      const int c = n0 + Rn + (j << 4) + col;
      const float bv = bias[c];
      #pragma unroll
      for (int rg = 0; rg < 4; ++rg)
        Cm[(size_t)(rbase + rg) * ldc + c] = acc[i][j][rg] + bv;
    }
  }
}

// ---------------------------------------------------------------------------
// proj partial: part[bh][tch] (128x64) = E_h[:, trange] @ KV_b[trange, :]
// KV is [M][C] fp32 (one of k or v in the shared region). grid (128, TCH).
// ---------------------------------------------------------------------------
__global__ __launch_bounds__(256) void proj_partial(
    const float* __restrict__ kv, const float* __restrict__ EF,
    float* __restrict__ part)
{
  const int bh = blockIdx.x;
  const int tch = blockIdx.y;
  const int b = bh >> 4;
  const int h = bh & 15;
  const float* Emat = EF + (size_t)h * KP * T_;
  const float* Kg = kv + (size_t)b * T_ * C_ + h * D_;
  float* outp = part + ((size_t)bh * TCH + tch) * KP * D_;
  const int tlo = tch * (T_ / TCH), thi = tlo + (T_ / TCH);

  __shared__ float Es[16][KP + 1];   // transposed [t][kk]
  __shared__ float Ks[16][D_];       // [t][d]
  const int tid = threadIdx.x;
  const int cg = tid & 15;
  const int rg = tid >> 4;
  const int ekk = tid >> 2;
  const int etc = (tid & 3) << 2;
  const int ktl = tid >> 4;
  const int kdc = (tid & 15) << 2;

  float acc[8][4];
  #pragma unroll
  for (int i = 0; i < 8; ++i)
    #pragma unroll
    for (int j = 0; j < 4; ++j) acc[i][j] = 0.f;

  for (int t0 = tlo; t0 < thi; t0 += 16) {
    #pragma unroll
    for (int l = 0; l < 2; ++l) {
      const float4 ev = *reinterpret_cast<const float4*>(
          &Emat[(size_t)(ekk + l * 64) * T_ + t0 + etc]);
      Es[etc + 0][ekk + l * 64] = ev.x;
      Es[etc + 1][ekk + l * 64] = ev.y;
      Es[etc + 2][ekk + l * 64] = ev.z;
      Es[etc + 3][ekk + l * 64] = ev.w;
    }
    *reinterpret_cast<float4*>(&Ks[ktl][kdc]) =
        *reinterpret_cast<const float4*>(&Kg[(size_t)(t0 + ktl) * C_ + kdc]);
    __syncthreads();
    #pragma unroll
    for (int tt = 0; tt < 16; ++tt) {
      float e[8], kvv[4];
      #pragma unroll
      for (int i = 0; i < 4; ++i) {
        e[i]     = Es[tt][rg * 4 + i];
        e[4 + i] = Es[tt][64 + rg * 4 + i];
      }
      #pragma unroll
      for (int j = 0; j < 4; ++j) kvv[j] = Ks[tt][cg * 4 + j];
      #pragma unroll
      for (int i = 0; i < 8; ++i)
        #pragma unroll
        for (int j = 0; j < 4; ++j)
          acc[i][j] += e[i] * kvv[j];
    }
    __syncthreads();
  }
  #pragma unroll
  for (int i = 0; i < 8; ++i) {
    const int kk = (i < 4) ? (rg * 4 + i) : (64 + rg * 4 + i - 4);
    const float4 o = make_float4(acc[i][0], acc[i][1], acc[i][2], acc[i][3]);
    *reinterpret_cast<float4*>(&outp[kk * D_ + cg * 4]) = o;
  }
}

// Sum the TCH partials: out[bh][i] = sum_c part[bh][c][i], i over KP*D=8192.
__global__ __launch_bounds__(256) void reduce_partials(
    const float* __restrict__ part, float* __restrict__ out)
{
  const int idx = blockIdx.x * 256 + threadIdx.x;   // over 128*8192
  const int bh = idx >> 13;
  const int i = idx & 8191;
  float s = 0.f;
  #pragma unroll
  for (int c = 0; c < TCH; ++c)
    s += part[((size_t)bh * TCH + c) * 8192 + i];
  out[(size_t)bh * 8192 + i] = s;
}

// ---------------------------------------------------------------------------
// Attention core (fp32): q from [M][C] region; writes y as hi/lo bf16 [M][C].
// ---------------------------------------------------------------------------
__global__ __launch_bounds__(256) void attn_core(
    const float* __restrict__ q, const float* __restrict__ kproj,
    const float* __restrict__ vproj, unsigned short* __restrict__ yhi,
    unsigned short* __restrict__ ylo)
{
  constexpr int TT = 32;
  constexpr int PITCH = 68;
  const int nchunk = T_ / TT;
  const int blk = blockIdx.x;
  const int bh = blk / nchunk;
  const int tch = blk % nchunk;
  const int b = bh >> 4, h = bh & 15;
  const int t0 = tch * TT;

  __shared__ float KVs[KP][PITCH];
  __shared__ float qs[TT][PITCH];
  __shared__ float att[TT][KP + 1];

  const int tid = threadIdx.x;

  {
    const float* qg = q + (size_t)(b * T_ + t0) * C_ + h * D_;
    #pragma unroll
    for (int l = 0; l < 2; ++l) {
      const int idx = tid + l * 256;
      const int tl = idx >> 4;
      const int dc = (idx & 15) << 2;
      *reinterpret_cast<float4*>(&qs[tl][dc]) =
          *reinterpret_cast<const float4*>(&qg[(size_t)tl * C_ + dc]);
    }
  }
  {
    const float* kp = kproj + (size_t)bh * KP * D_;
    #pragma unroll
    for (int l = 0; l < 8; ++l) {
      const int idx = tid + l * 256;
      const int kk = idx >> 4;
      const int dc = (idx & 15) << 2;
      *reinterpret_cast<float4*>(&KVs[kk][dc]) =
          *reinterpret_cast<const float4*>(&kp[(size_t)kk * D_ + dc]);
    }
  }
  __syncthreads();

  const int kset = tid & 31;
  const int rowg = tid >> 5;
  float lg[4][4];
  #pragma unroll
  for (int i = 0; i < 4; ++i)
    #pragma unroll
    for (int j = 0; j < 4; ++j) lg[i][j] = 0.f;

  for (int d0 = 0; d0 < D_; d0 += 4) {
    float4 q4[4], k4[4];
    #pragma unroll
    for (int i = 0; i < 4; ++i)
      q4[i] = *reinterpret_cast<const float4*>(&qs[rowg * 4 + i][d0]);
    #pragma unroll
    for (int j = 0; j < 4; ++j)
      k4[j] = *reinterpret_cast<const float4*>(&KVs[kset + 32 * j][d0]);
    #pragma unroll
    for (int i = 0; i < 4; ++i)
      #pragma unroll
      for (int j = 0; j < 4; ++j)
        lg[i][j] += q4[i].x * k4[j].x + q4[i].y * k4[j].y +
                    q4[i].z * k4[j].z + q4[i].w * k4[j].w;
  }

  const float scale = 0.125f;
  #pragma unroll
  for (int i = 0; i < 4; ++i) {
    float mx = -1e30f;
    #pragma unroll
    for (int j = 0; j < 4; ++j) { lg[i][j] *= scale; mx = fmaxf(mx, lg[i][j]); }
    #pragma unroll
    for (int s = 16; s >= 1; s >>= 1) mx = fmaxf(mx, __shfl_xor(mx, s, 64));
    float e[4], sum = 0.f;
    #pragma unroll
    for (int j = 0; j < 4; ++j) { e[j] = __expf(lg[i][j] - mx); sum += e[j]; }
    #pragma unroll
    for (int s = 16; s >= 1; s >>= 1) sum += __shfl_xor(sum, s, 64);
    const float inv = 1.f / sum;
    #pragma unroll
    for (int j = 0; j < 4; ++j) att[rowg * 4 + i][kset + 32 * j] = e[j] * inv;
  }
  __syncthreads();

  {
    const float* vp = vproj + (size_t)bh * KP * D_;
    #pragma unroll
    for (int l = 0; l < 8; ++l) {
      const int idx = tid + l * 256;
      const int kk = idx >> 4;
      const int dc = (idx & 15) << 2;
      *reinterpret_cast<float4*>(&KVs[kk][dc]) =
          *reinterpret_cast<const float4*>(&vp[(size_t)kk * D_ + dc]);
    }
  }
  __syncthreads();

  const int dg = tid & 15;
  const int rowg2 = tid >> 4;
  float yacc[2][4];
  #pragma unroll
  for (int i = 0; i < 2; ++i)
    #pragma unroll
    for (int j = 0; j < 4; ++j) yacc[i][j] = 0.f;

  for (int kk = 0; kk < KP; ++kk) {
    const float w0 = att[rowg2 * 2 + 0][kk];
    const float w1 = att[rowg2 * 2 + 1][kk];
    const float4 v4 = *reinterpret_cast<const float4*>(&KVs[kk][dg * 4]);
    yacc[0][0] += w0 * v4.x; yacc[0][1] += w0 * v4.y;
    yacc[0][2] += w0 * v4.z; yacc[0][3] += w0 * v4.w;
    yacc[1][0] += w1 * v4.x; yacc[1][1] += w1 * v4.y;
    yacc[1][2] += w1 * v4.z; yacc[1][3] += w1 * v4.w;
  }
  #pragma unroll
  for (int i = 0; i < 2; ++i) {
    const int t = t0 + rowg2 * 2 + i;
    const size_t o = (size_t)(b * T_ + t) * C_ + h * D_ + dg * 4;
    ushort4 hv, lv;
    hv.x = f2bf(yacc[i][0]); lv.x = f2bf(yacc[i][0] - bf2f(hv.x));
    hv.y = f2bf(yacc[i][1]); lv.y = f2bf(yacc[i][1] - bf2f(hv.y));
    hv.z = f2bf(yacc[i][2]); lv.z = f2bf(yacc[i][2] - bf2f(hv.z));
    hv.w = f2bf(yacc[i][3]); lv.w = f2bf(yacc[i][3] - bf2f(hv.w));
    *reinterpret_cast<ushort4*>(yhi + o) = hv;
    *reinterpret_cast<ushort4*>(ylo + o) = lv;
  }
}

// ---------------------------------------------------------------------------
extern "C" void kernel_launch(void* const* d_in, const int* in_sizes, int n_in,
                              void* d_out, int out_size, void* d_ws, size_t ws_size,
                              hipStream_t stream) {
  (void)in_sizes; (void)n_in; (void)out_size; (void)ws_size;
  const float* x      = (const float*)d_in[0];
  const float* W_attn = (const float*)d_in[1];
  const float* b_attn = (const float*)d_in[2];
  const float* W_proj = (const float*)d_in[3];
  const float* b_proj = (const float*)d_in[4];
  const float* E      = (const float*)d_in[5];
  const float* F      = (const float*)d_in[6];
  float* out = (float*)d_out;
  char* ws = (char*)d_ws;

  // ws regions, 182 MB peak (Round 1's 209.7 MB proved safe; 284 MB crashed):
  float* kvq  = (float*)ws;                              // [M][C] fp32, 67.1 MB
  unsigned short* xhi = (unsigned short*)(ws + (size_t)67108864);
  unsigned short* xlo = xhi + (size_t)M_ * C_;           // 67.1 MB both (reused as y)
  unsigned short* WaThi = xlo + (size_t)M_ * C_;         // [3072][1024] 6.3 MB
  unsigned short* WaTlo = WaThi + (size_t)C3 * C_;       // 6.3 MB
  unsigned short* WpT   = WaTlo + (size_t)C3 * C_;       // [1024][1024] 2.1 MB
  float* kproj = (float*)(WpT + (size_t)C_ * C_);        // 4.2 MB
  float* vproj = kproj + (size_t)B_ * H_ * KP * D_;      // 4.2 MB
  float* part  = vproj + (size_t)B_ * H_ * KP * D_;      // 33.6 MB
  unsigned short* yhi = xhi;                             // reuse after q-GEMM
  unsigned short* ylo = xlo;

  // 0) precision splits / transposes
  split_rm<<<(M_ * C_ / 4 + 255) / 256, 256, 0, stream>>>(x, xhi, xlo, M_ * C_ / 4);
  split_tr<<<dim3(C3 / 32, C_ / 32), 256, 0, stream>>>(W_attn, WaThi, WaTlo, C_, C3);
  split_tr<<<dim3(C_ / 32, C_ / 32), 256, 0, stream>>>(W_proj, WpT, nullptr, C_, C_);

  // 1) k = x @ Wk + bk  -> kvq;  kproj = E @ k (partials + reduce)
  gemm_mfma_split<3><<<dim3(C_ / 128, M_ / 128), 256, 0, stream>>>(
      xhi, xlo, WaThi + (size_t)C_ * K_, WaTlo + (size_t)C_ * K_,
      b_attn + C_, kvq, C_);
  proj_partial<<<dim3(B_ * H_, TCH), 256, 0, stream>>>(kvq, E, part);
  reduce_partials<<<(B_ * H_ * KP * D_) / 256, 256, 0, stream>>>(part, kproj);

  // 2) v = x @ Wv + bv  -> kvq (overwrite);  vproj = F @ v
  gemm_mfma_split<3><<<dim3(C_ / 128, M_ / 128), 256, 0, stream>>>(
      xhi, xlo, WaThi + (size_t)2 * C_ * K_, WaTlo + (size_t)2 * C_ * K_,
      b_attn + 2 * C_, kvq, C_);
  proj_partial<<<dim3(B_ * H_, TCH), 256, 0, stream>>>(kvq, F, part);
  reduce_partials<<<(B_ * H_ * KP * D_) / 256, 256, 0, stream>>>(part, vproj);

  // 3) q = x @ Wq + bq  -> kvq (overwrite)
  gemm_mfma_split<3><<<dim3(C_ / 128, M_ / 128), 256, 0, stream>>>(
      xhi, xlo, WaThi, WaTlo, b_attn, kvq, C_);

  // 4) attention core -> y (hi/lo bf16, overwrites x splits)
  attn_core<<<dim3(B_ * H_ * (T_ / 32)), 256, 0, stream>>>(
      kvq, kproj, vproj, yhi, ylo);

  // 5) out = y @ W_proj + b_proj
  gemm_mfma_split<2><<<dim3(C_ / 128, M_ / 128), 256, 0, stream>>>(
      yhi, ylo, WpT, nullptr, b_proj, out, C_);
}

// Round 4
// 758.526 us; speedup vs baseline: 2.5742x; 1.1923x over previous
//
#include <hip/hip_runtime.h>
#include <math.h>

// LinformerAttention on MI355X — Round 4: attention core moved to MFMA
// (S^T = Kp@Q^T -> shuffle softmax -> y = P@V with pre-transposed V).
// Dense GEMMs unchanged (split-bf16 MFMA, R3-verified). ws peak 188.7 MB.
// B=8 T=2048 C=1024 H=16 D=64 Kproj=128.

constexpr int B_ = 8, T_ = 2048, C_ = 1024, H_ = 16, D_ = 64, KP = 128;
constexpr int M_ = B_ * T_;            // 16384
constexpr int C3 = 3 * C_;             // 3072
constexpr int K_ = C_;                 // GEMM K = 1024 for all MFMA GEMMs
constexpr int TCH = 8;                 // proj T-chunks (parallelism)

typedef __attribute__((ext_vector_type(8))) short bf16x8;   // 8 bf16 = 4 VGPR
typedef __attribute__((ext_vector_type(4))) float f32x4;

__device__ __forceinline__ unsigned short f2bf(float f) {
  unsigned u = __builtin_bit_cast(unsigned, f);
  u += 0x7FFFu + ((u >> 16) & 1u);     // round-to-nearest-even
  return (unsigned short)(u >> 16);
}
__device__ __forceinline__ float bf2f(unsigned short h) {
  unsigned u = ((unsigned)h) << 16;
  return __builtin_bit_cast(float, u);
}

#define GLOAD_LDS16(gptr, lptr)                                                \
  __builtin_amdgcn_global_load_lds(                                            \
      (const __attribute__((address_space(1))) void*)(gptr),                   \
      (__attribute__((address_space(3))) void*)(lptr), 16, 0, 0)

// ---------------------------------------------------------------------------
// Split fp32 row-major array into hi/lo bf16 (same layout). n4 = n/4.
// ---------------------------------------------------------------------------
__global__ __launch_bounds__(256) void split_rm(
    const float* __restrict__ in, unsigned short* __restrict__ hi,
    unsigned short* __restrict__ lo, int n4)
{
  int i = blockIdx.x * 256 + threadIdx.x;
  if (i >= n4) return;
  const float4 v = reinterpret_cast<const float4*>(in)[i];
  ushort4 h, l;
  h.x = f2bf(v.x); l.x = f2bf(v.x - bf2f(h.x));
  h.y = f2bf(v.y); l.y = f2bf(v.y - bf2f(h.y));
  h.z = f2bf(v.z); l.z = f2bf(v.z - bf2f(h.z));
  h.w = f2bf(v.w); l.w = f2bf(v.w - bf2f(h.w));
  reinterpret_cast<ushort4*>(hi)[i] = h;
  reinterpret_cast<ushort4*>(lo)[i] = l;
}

// ---------------------------------------------------------------------------
// Transpose + split: W [rows][cols] fp32 -> Thi/Tlo [cols][rows] bf16.
// Tlo may be null. 32x32 LDS tile.
// ---------------------------------------------------------------------------
__global__ __launch_bounds__(256) void split_tr(
    const float* __restrict__ W, unsigned short* __restrict__ Thi,
    unsigned short* __restrict__ Tlo, int rows, int cols)
{
  __shared__ float tile[32][33];
  const int c0 = blockIdx.x * 32, r0 = blockIdx.y * 32;
  const int tx = threadIdx.x & 31, ty = threadIdx.x >> 5;   // ty 0..7
  #pragma unroll
  for (int i = 0; i < 4; ++i)
    tile[ty + i * 8][tx] = W[(size_t)(r0 + ty + i * 8) * cols + c0 + tx];
  __syncthreads();
  #pragma unroll
  for (int i = 0; i < 4; ++i) {
    const int cr = ty + i * 8;
    const float v = tile[tx][cr];                 // = W[r0+tx][c0+cr]
    const size_t o = (size_t)(c0 + cr) * rows + r0 + tx;
    const unsigned short h = f2bf(v);
    Thi[o] = h;
    if (Tlo) Tlo[o] = f2bf(v - bf2f(h));
  }
}

// ---------------------------------------------------------------------------
// Split-bf16 MFMA GEMM (R3-verified): C(fp32,16384xN) = (Ahi+Alo)(MxK)*B + bias.
// BThi/BTlo are [N][K] bf16, K=1024. NPROD==3: AhBh+AlBh+AhBl. NPROD==2: no AhBl.
// ---------------------------------------------------------------------------
template <int NPROD>
__global__ __launch_bounds__(256) void gemm_mfma_split(
    const unsigned short* __restrict__ Ahi, const unsigned short* __restrict__ Alo,
    const unsigned short* __restrict__ BThi, const unsigned short* __restrict__ BTlo,
    const float* __restrict__ bias, float* __restrict__ Cm, int ldc)
{
  constexpr int NBUF = (NPROD == 3) ? 4 : 3;
  __shared__ unsigned short lds[NBUF * 4096];      // 4096 bf16 = 128x32 per buf
  unsigned short* sAhi = lds;
  unsigned short* sAlo = lds + 4096;
  unsigned short* sBhi = lds + 8192;
  unsigned short* sBlo = lds + 12288;

  const int tid  = threadIdx.x;
  const int lane = tid & 63;
  const int wid  = tid >> 6;
  const int m0 = blockIdx.y * 128;
  const int n0 = blockIdx.x * 128;

  const int srow  = lane >> 2;
  const int skseg = (lane & 3) << 3;
  const int col  = lane & 15;
  const int quad = lane >> 4;
  const int Rm = (wid >> 1) << 6;
  const int Rn = (wid & 1) << 6;

  f32x4 acc[4][4];
  #pragma unroll
  for (int i = 0; i < 4; ++i)
    #pragma unroll
    for (int j = 0; j < 4; ++j)
      acc[i][j] = (f32x4){0.f, 0.f, 0.f, 0.f};

  for (int k0 = 0; k0 < K_; k0 += 32) {
    #pragma unroll
    for (int r = 0; r < 2; ++r) {
      const int chunk = (r << 2) + wid;
      const int row = (chunk << 4) + srow;
      const int ldso = chunk << 9;
      const size_t ga = (size_t)(m0 + row) * K_ + k0 + skseg;
      const size_t gb = (size_t)(n0 + row) * K_ + k0 + skseg;
      GLOAD_LDS16(Ahi + ga, sAhi + ldso);
      GLOAD_LDS16(Alo + ga, sAlo + ldso);
      GLOAD_LDS16(BThi + gb, sBhi + ldso);
      if constexpr (NPROD == 3) GLOAD_LDS16(BTlo + gb, sBlo + ldso);
    }
    __syncthreads();

    bf16x8 ah[4], al[4], bh[4], bl[4];
    #pragma unroll
    for (int t = 0; t < 4; ++t) {
      const int ao = ((Rm + (t << 4) + col) << 5) + (quad << 3);
      ah[t] = *reinterpret_cast<const bf16x8*>(sAhi + ao);
      al[t] = *reinterpret_cast<const bf16x8*>(sAlo + ao);
      const int bo = ((Rn + (t << 4) + col) << 5) + (quad << 3);
      bh[t] = *reinterpret_cast<const bf16x8*>(sBhi + bo);
      if constexpr (NPROD == 3)
        bl[t] = *reinterpret_cast<const bf16x8*>(sBlo + bo);
    }
    #pragma unroll
    for (int i = 0; i < 4; ++i)
      #pragma unroll
      for (int j = 0; j < 4; ++j) {
        acc[i][j] = __builtin_amdgcn_mfma_f32_16x16x32_bf16(ah[i], bh[j], acc[i][j], 0, 0, 0);
        acc[i][j] = __builtin_amdgcn_mfma_f32_16x16x32_bf16(al[i], bh[j], acc[i][j], 0, 0, 0);
        if constexpr (NPROD == 3)
          acc[i][j] = __builtin_amdgcn_mfma_f32_16x16x32_bf16(ah[i], bl[j], acc[i][j], 0, 0, 0);
      }
    __syncthreads();
  }

  #pragma unroll
  for (int i = 0; i < 4; ++i) {
    const int rbase = m0 + Rm + (i << 4) + (quad << 2);
    #pragma unroll
    for (int j = 0; j < 4; ++j) {
      const int c = n0 + Rn + (j << 4) + col;
      const float bv = bias[c];
      #pragma unroll
      for (int rg = 0; rg < 4; ++rg)
        Cm[(size_t)(rbase + rg) * ldc + c] = acc[i][j][rg] + bv;
    }
  }
}

// ---------------------------------------------------------------------------
// proj partial (R3-verified): part[bh][tch] (128x64) = E_h[:,trange]@KV[trange,:]
// ---------------------------------------------------------------------------
__global__ __launch_bounds__(256) void proj_partial(
    const float* __restrict__ kv, const float* __restrict__ EF,
    float* __restrict__ part)
{
  const int bh = blockIdx.x;
  const int tch = blockIdx.y;
  const int b = bh >> 4;
  const int h = bh & 15;
  const float* Emat = EF + (size_t)h * KP * T_;
  const float* Kg = kv + (size_t)b * T_ * C_ + h * D_;
  float* outp = part + ((size_t)bh * TCH + tch) * KP * D_;
  const int tlo = tch * (T_ / TCH), thi = tlo + (T_ / TCH);

  __shared__ float Es[16][KP + 1];
  __shared__ float Ks[16][D_];
  const int tid = threadIdx.x;
  const int cg = tid & 15;
  const int rg = tid >> 4;
  const int ekk = tid >> 2;
  const int etc = (tid & 3) << 2;
  const int ktl = tid >> 4;
  const int kdc = (tid & 15) << 2;

  float acc[8][4];
  #pragma unroll
  for (int i = 0; i < 8; ++i)
    #pragma unroll
    for (int j = 0; j < 4; ++j) acc[i][j] = 0.f;

  for (int t0 = tlo; t0 < thi; t0 += 16) {
    #pragma unroll
    for (int l = 0; l < 2; ++l) {
      const float4 ev = *reinterpret_cast<const float4*>(
          &Emat[(size_t)(ekk + l * 64) * T_ + t0 + etc]);
      Es[etc + 0][ekk + l * 64] = ev.x;
      Es[etc + 1][ekk + l * 64] = ev.y;
      Es[etc + 2][ekk + l * 64] = ev.z;
      Es[etc + 3][ekk + l * 64] = ev.w;
    }
    *reinterpret_cast<float4*>(&Ks[ktl][kdc]) =
        *reinterpret_cast<const float4*>(&Kg[(size_t)(t0 + ktl) * C_ + kdc]);
    __syncthreads();
    #pragma unroll
    for (int tt = 0; tt < 16; ++tt) {
      float e[8], kvv[4];
      #pragma unroll
      for (int i = 0; i < 4; ++i) {
        e[i]     = Es[tt][rg * 4 + i];
        e[4 + i] = Es[tt][64 + rg * 4 + i];
      }
      #pragma unroll
      for (int j = 0; j < 4; ++j) kvv[j] = Ks[tt][cg * 4 + j];
      #pragma unroll
      for (int i = 0; i < 8; ++i)
        #pragma unroll
        for (int j = 0; j < 4; ++j)
          acc[i][j] += e[i] * kvv[j];
    }
    __syncthreads();
  }
  #pragma unroll
  for (int i = 0; i < 8; ++i) {
    const int kk = (i < 4) ? (rg * 4 + i) : (64 + rg * 4 + i - 4);
    const float4 o = make_float4(acc[i][0], acc[i][1], acc[i][2], acc[i][3]);
    *reinterpret_cast<float4*>(&outp[kk * D_ + cg * 4]) = o;
  }
}

// ---------------------------------------------------------------------------
// reduce_k: kprojh[bh][kk][d] (bf16 single) = sum_c part[bh][c][kk][d]
// ---------------------------------------------------------------------------
__global__ __launch_bounds__(256) void reduce_k(
    const float* __restrict__ part, unsigned short* __restrict__ kprojh)
{
  const int idx = blockIdx.x * 256 + threadIdx.x;   // over 128*8192
  const int bh = idx >> 13;
  const int i = idx & 8191;
  float s = 0.f;
  #pragma unroll
  for (int c = 0; c < TCH; ++c)
    s += part[((size_t)bh * TCH + c) * 8192 + i];
  kprojh[idx] = f2bf(s);
}

// ---------------------------------------------------------------------------
// reduce_v: vpT hi/lo [bh][d][kk] (bf16) = transpose(sum_c part[bh][c][kk][d])
// One block per bh; LDS transpose with pitch 66 (bank-safe).
// ---------------------------------------------------------------------------
__global__ __launch_bounds__(256) void reduce_v(
    const float* __restrict__ part, unsigned short* __restrict__ vpTh,
    unsigned short* __restrict__ vpTl)
{
  __shared__ float sums[KP * 66];     // [kk][d] pitch 66, 33.8 KB
  const int bh = blockIdx.x;
  const int tid = threadIdx.x;
  #pragma unroll
  for (int j = 0; j < 32; ++j) {
    const int i = j * 256 + tid;      // kk = i>>6, d = i&63
    float s = 0.f;
    #pragma unroll
    for (int c = 0; c < TCH; ++c)
      s += part[((size_t)bh * TCH + c) * 8192 + i];
    sums[(i >> 6) * 66 + (i & 63)] = s;
  }
  __syncthreads();
  #pragma unroll
  for (int j = 0; j < 32; ++j) {
    const int i = j * 256 + tid;      // d = i>>7, kk = i&127
    const float s = sums[(i & 127) * 66 + (i >> 7)];
    const unsigned short h = f2bf(s);
    vpTh[(size_t)bh * 8192 + i] = h;
    vpTl[(size_t)bh * 8192 + i] = f2bf(s - bf2f(h));
  }
}

// ---------------------------------------------------------------------------
// MFMA attention core. Per block: one (b,h) and 64 q-rows (t-tile).
//   S^T(128kk x 64t) = Kp(A, single bf16) @ Q^T(B, hi/lo)     [2-product]
//   softmax over kk: per-lane partials + shfl_xor(16,32) (t = lane&15)
//   P (unnormalized, single bf16) -> LDS [t][kk]
//   y(64t x 64d)     = P(A) @ V(B via vpT hi/lo)              [2-product]
//   epilogue scales by 1/rowsum, emits y hi/lo bf16 [M][C].
// 4 waves: wave w owns t-strip [w*16, w*16+16).
// ---------------------------------------------------------------------------
__global__ __launch_bounds__(256) void attn_mfma(
    const float* __restrict__ q, const unsigned short* __restrict__ kprojh,
    const unsigned short* __restrict__ vpTh, const unsigned short* __restrict__ vpTl,
    unsigned short* __restrict__ yhi, unsigned short* __restrict__ ylo)
{
  // LDS union (52480 B): phase A: Qh@0(9216) Ql@9216 Kp@18432(18432) end 36864
  //                      phase B: Vh@0(17408) Vl@17408 P@34816(17408) atts@52224
  __shared__ __attribute__((aligned(16))) char lds[52480];
  unsigned short* Qh = (unsigned short*)(lds);
  unsigned short* Ql = (unsigned short*)(lds + 9216);
  unsigned short* Kp = (unsigned short*)(lds + 18432);
  unsigned short* Vh = (unsigned short*)(lds);
  unsigned short* Vl = (unsigned short*)(lds + 17408);
  unsigned short* Ps = (unsigned short*)(lds + 34816);
  float* atts = (float*)(lds + 52224);

  const int tid  = threadIdx.x;
  const int lane = tid & 63;
  const int w    = tid >> 6;
  const int col  = lane & 15;
  const int quad = lane >> 4;
  const int bh = blockIdx.x >> 5;          // 128 bh
  const int tch = blockIdx.x & 31;         // 32 t-tiles of 64
  const int b = bh >> 4, h = bh & 15;
  const int t0 = tch * 64;

  // ---- phase A staging: Q (fp32 -> hi/lo bf16, pitch 72), Kp (pitch 72) ----
  {
    const float* qg = q + (size_t)(b * T_ + t0) * C_ + h * D_;
    #pragma unroll
    for (int l = 0; l < 4; ++l) {
      const int idx = l * 256 + tid;
      const int t = idx >> 4, dc = (idx & 15) << 2;
      const float4 v = *reinterpret_cast<const float4*>(qg + (size_t)t * C_ + dc);
      ushort4 hv, lv;
      hv.x = f2bf(v.x); lv.x = f2bf(v.x - bf2f(hv.x));
      hv.y = f2bf(v.y); lv.y = f2bf(v.y - bf2f(hv.y));
      hv.z = f2bf(v.z); lv.z = f2bf(v.z - bf2f(hv.z));
      hv.w = f2bf(v.w); lv.w = f2bf(v.w - bf2f(hv.w));
      *reinterpret_cast<ushort4*>(Qh + t * 72 + dc) = hv;
      *reinterpret_cast<ushort4*>(Ql + t * 72 + dc) = lv;
    }
    const unsigned short* kg = kprojh + (size_t)bh * 8192;
    #pragma unroll
    for (int l = 0; l < 8; ++l) {
      const int idx = l * 256 + tid;
      const int kk = idx >> 4, dc = (idx & 15) << 2;
      *reinterpret_cast<ushort4*>(Kp + kk * 72 + dc) =
          *reinterpret_cast<const ushort4*>(kg + kk * 64 + dc);
    }
  }
  __syncthreads();

  // ---- S^T MFMA: m=kk (8 tiles), n=t (this wave's strip), k=d (2 steps) ----
  f32x4 s[8];
  #pragma unroll
  for (int i = 0; i < 8; ++i) s[i] = (f32x4){0.f, 0.f, 0.f, 0.f};
  bf16x8 bqh[2], bql[2];
  #pragma unroll
  for (int ks = 0; ks < 2; ++ks) {
    const int off = (w * 16 + col) * 72 + ks * 32 + quad * 8;
    bqh[ks] = *reinterpret_cast<const bf16x8*>(Qh + off);
    bql[ks] = *reinterpret_cast<const bf16x8*>(Ql + off);
  }
  #pragma unroll
  for (int i = 0; i < 8; ++i)
    #pragma unroll
    for (int ks = 0; ks < 2; ++ks) {
      const bf16x8 a = *reinterpret_cast<const bf16x8*>(
          Kp + (i * 16 + col) * 72 + ks * 32 + quad * 8);
      s[i] = __builtin_amdgcn_mfma_f32_16x16x32_bf16(a, bqh[ks], s[i], 0, 0, 0);
      s[i] = __builtin_amdgcn_mfma_f32_16x16x32_bf16(a, bql[ks], s[i], 0, 0, 0);
    }

  // ---- softmax over kk (reg partials + shfl over quads); t = w*16+col ----
  float mx = -3.0e38f;
  #pragma unroll
  for (int i = 0; i < 8; ++i)
    #pragma unroll
    for (int rg = 0; rg < 4; ++rg) {
      s[i][rg] *= 0.125f;
      mx = fmaxf(mx, s[i][rg]);
    }
  mx = fmaxf(mx, __shfl_xor(mx, 16));
  mx = fmaxf(mx, __shfl_xor(mx, 32));
  float sum = 0.f;
  #pragma unroll
  for (int i = 0; i < 8; ++i)
    #pragma unroll
    for (int rg = 0; rg < 4; ++rg) {
      const float e = __expf(s[i][rg] - mx);
      s[i][rg] = e;
      sum += e;
    }
  sum += __shfl_xor(sum, 16);
  sum += __shfl_xor(sum, 32);
  const float inv = 1.f / sum;
  __syncthreads();   // all waves done reading Q/Kp

  // ---- phase B staging: Vp hi/lo (pitch 136); P store [t][kk]; atts ----
  {
    const unsigned short* vgh = vpTh + (size_t)bh * 8192;
    const unsigned short* vgl = vpTl + (size_t)bh * 8192;
    #pragma unroll
    for (int l = 0; l < 8; ++l) {
      const int idx = l * 256 + tid;
      const int d = idx >> 5, kc = (idx & 31) << 2;
      *reinterpret_cast<ushort4*>(Vh + d * 136 + kc) =
          *reinterpret_cast<const ushort4*>(vgh + d * 128 + kc);
      *reinterpret_cast<ushort4*>(Vl + d * 136 + kc) =
          *reinterpret_cast<const ushort4*>(vgl + d * 128 + kc);
    }
  }
  #pragma unroll
  for (int i = 0; i < 8; ++i) {
    ushort4 hp;
    hp.x = f2bf(s[i][0]); hp.y = f2bf(s[i][1]);
    hp.z = f2bf(s[i][2]); hp.w = f2bf(s[i][3]);
    *reinterpret_cast<ushort4*>(Ps + (w * 16 + col) * 136 + i * 16 + quad * 4) = hp;
  }
  if (quad == 0) atts[w * 16 + col] = inv;
  __syncthreads();

  // ---- y = P @ V: m=t (wave strip), n=d (4 tiles), k=kk (4 steps) ----
  f32x4 y[4];
  #pragma unroll
  for (int j = 0; j < 4; ++j) y[j] = (f32x4){0.f, 0.f, 0.f, 0.f};
  bf16x8 ap[4];
  #pragma unroll
  for (int ks = 0; ks < 4; ++ks)
    ap[ks] = *reinterpret_cast<const bf16x8*>(
        Ps + (w * 16 + col) * 136 + ks * 32 + quad * 8);
  #pragma unroll
  for (int j = 0; j < 4; ++j)
    #pragma unroll
    for (int ks = 0; ks < 4; ++ks) {
      const int off = (j * 16 + col) * 136 + ks * 32 + quad * 8;
      const bf16x8 bvh = *reinterpret_cast<const bf16x8*>(Vh + off);
      const bf16x8 bvl = *reinterpret_cast<const bf16x8*>(Vl + off);
      y[j] = __builtin_amdgcn_mfma_f32_16x16x32_bf16(ap[ks], bvh, y[j], 0, 0, 0);
      y[j] = __builtin_amdgcn_mfma_f32_16x16x32_bf16(ap[ks], bvl, y[j], 0, 0, 0);
    }

  // ---- epilogue: scale by 1/rowsum, write y hi/lo [M][C] ----
  const f32x4 inv4 = *reinterpret_cast<const f32x4*>(atts + w * 16 + quad * 4);
  #pragma unroll
  for (int j = 0; j < 4; ++j)
    #pragma unroll
    for (int rg = 0; rg < 4; ++rg) {
      const int t = t0 + w * 16 + quad * 4 + rg;
      const int d = j * 16 + col;
      const float val = y[j][rg] * inv4[rg];
      const size_t o = (size_t)(b * T_ + t) * C_ + h * D_ + d;
      const unsigned short hv = f2bf(val);
      yhi[o] = hv;
      ylo[o] = f2bf(val - bf2f(hv));
    }
}

// ---------------------------------------------------------------------------
extern "C" void kernel_launch(void* const* d_in, const int* in_sizes, int n_in,
                              void* d_out, int out_size, void* d_ws, size_t ws_size,
                              hipStream_t stream) {
  (void)in_sizes; (void)n_in; (void)out_size; (void)ws_size;
  const float* x      = (const float*)d_in[0];
  const float* W_attn = (const float*)d_in[1];
  const float* b_attn = (const float*)d_in[2];
  const float* W_proj = (const float*)d_in[3];
  const float* b_proj = (const float*)d_in[4];
  const float* E      = (const float*)d_in[5];
  const float* F      = (const float*)d_in[6];
  float* out = (float*)d_out;
  char* ws = (char*)d_ws;

  // ws regions, 188.7 MB peak (209.7 MB proved safe in R1; 284 MB crashed):
  float* kvq  = (float*)ws;                              // [M][C] fp32, 67.1 MB
  unsigned short* xhi = (unsigned short*)(ws + (size_t)67108864);
  unsigned short* xlo = xhi + (size_t)M_ * C_;           // 67.1 MB both (reused as y)
  unsigned short* WaThi = xlo + (size_t)M_ * C_;         // 6.3 MB
  unsigned short* WaTlo = WaThi + (size_t)C3 * C_;       // 6.3 MB
  unsigned short* WpT   = WaTlo + (size_t)C3 * C_;       // 2.1 MB
  float* part = (float*)(WpT + (size_t)C_ * C_);         // 33.6 MB
  unsigned short* kprojh = (unsigned short*)(part + (size_t)B_ * H_ * TCH * KP * D_);
  unsigned short* vpTh   = kprojh + (size_t)B_ * H_ * KP * D_;  // 2.1 MB each
  unsigned short* vpTl   = vpTh + (size_t)B_ * H_ * KP * D_;
  unsigned short* yhi = xhi;                             // reuse after q-GEMM
  unsigned short* ylo = xlo;

  // 0) precision splits / transposes
  split_rm<<<(M_ * C_ / 4 + 255) / 256, 256, 0, stream>>>(x, xhi, xlo, M_ * C_ / 4);
  split_tr<<<dim3(C3 / 32, C_ / 32), 256, 0, stream>>>(W_attn, WaThi, WaTlo, C_, C3);
  split_tr<<<dim3(C_ / 32, C_ / 32), 256, 0, stream>>>(W_proj, WpT, nullptr, C_, C_);

  // 1) k = x @ Wk + bk -> kvq;  kproj = E @ k (partials + bf16 reduce)
  gemm_mfma_split<3><<<dim3(C_ / 128, M_ / 128), 256, 0, stream>>>(
      xhi, xlo, WaThi + (size_t)C_ * K_, WaTlo + (size_t)C_ * K_,
      b_attn + C_, kvq, C_);
  proj_partial<<<dim3(B_ * H_, TCH), 256, 0, stream>>>(kvq, E, part);
  reduce_k<<<(B_ * H_ * KP * D_) / 256, 256, 0, stream>>>(part, kprojh);

  // 2) v = x @ Wv + bv -> kvq;  vpT hi/lo = transpose(F @ v)
  gemm_mfma_split<3><<<dim3(C_ / 128, M_ / 128), 256, 0, stream>>>(
      xhi, xlo, WaThi + (size_t)2 * C_ * K_, WaTlo + (size_t)2 * C_ * K_,
      b_attn + 2 * C_, kvq, C_);
  proj_partial<<<dim3(B_ * H_, TCH), 256, 0, stream>>>(kvq, F, part);
  reduce_v<<<B_ * H_, 256, 0, stream>>>(part, vpTh, vpTl);

  // 3) q = x @ Wq + bq -> kvq
  gemm_mfma_split<3><<<dim3(C_ / 128, M_ / 128), 256, 0, stream>>>(
      xhi, xlo, WaThi, WaTlo, b_attn, kvq, C_);

  // 4) MFMA attention -> y hi/lo (overwrites x splits)
  attn_mfma<<<B_ * H_ * (T_ / 64), 256, 0, stream>>>(
      kvq, kprojh, vpTh, vpTl, yhi, ylo);

  // 5) out = y @ W_proj + b_proj
  gemm_mfma_split<2><<<dim3(C_ / 128, M_ / 128), 256, 0, stream>>>(
      yhi, ylo, WpT, nullptr, b_proj, out, C_);
}

// Round 5
// 616.790 us; speedup vs baseline: 3.1657x; 1.2298x over previous
//
#include <hip/hip_runtime.h>
#include <math.h>

// LinformerAttention on MI355X — Round 5:
//  * qkv GEMMs drop the W-lo product (2-product split-bf16: (xhi+xlo)@Whi)
//  * proj (E@k / F@v) moved to MFMA (E single bf16, k/v hi-lo via LDS transpose)
//  * bf16 hi/lo dataflow: GEMM epilogue emits hi/lo bf16; attn reads q hi/lo
//  ws peak 182.5 MB (R3-proven size). B=8 T=2048 C=1024 H=16 D=64 Kproj=128.

constexpr int B_ = 8, T_ = 2048, C_ = 1024, H_ = 16, D_ = 64, KP = 128;
constexpr int M_ = B_ * T_;            // 16384
constexpr int C3 = 3 * C_;             // 3072
constexpr int K_ = C_;                 // GEMM K = 1024
constexpr int TCH = 4;                 // proj K-chunks (t-chunks of 512)

typedef __attribute__((ext_vector_type(8))) short bf16x8;   // 8 bf16 = 4 VGPR
typedef __attribute__((ext_vector_type(4))) float f32x4;

__device__ __forceinline__ unsigned short f2bf(float f) {
  unsigned u = __builtin_bit_cast(unsigned, f);
  u += 0x7FFFu + ((u >> 16) & 1u);     // round-to-nearest-even
  return (unsigned short)(u >> 16);
}
__device__ __forceinline__ float bf2f(unsigned short h) {
  unsigned u = ((unsigned)h) << 16;
  return __builtin_bit_cast(float, u);
}

#define GLOAD_LDS16(gptr, lptr)                                                \
  __builtin_amdgcn_global_load_lds(                                            \
      (const __attribute__((address_space(1))) void*)(gptr),                   \
      (__attribute__((address_space(3))) void*)(lptr), 16, 0, 0)

// ---------------------------------------------------------------------------
// Split fp32 row-major into hi (and optionally lo) bf16. n4 = n/4.
// ---------------------------------------------------------------------------
__global__ __launch_bounds__(256) void split_rm(
    const float* __restrict__ in, unsigned short* __restrict__ hi,
    unsigned short* __restrict__ lo, int n4)
{
  int i = blockIdx.x * 256 + threadIdx.x;
  if (i >= n4) return;
  const float4 v = reinterpret_cast<const float4*>(in)[i];
  ushort4 h;
  h.x = f2bf(v.x); h.y = f2bf(v.y); h.z = f2bf(v.z); h.w = f2bf(v.w);
  reinterpret_cast<ushort4*>(hi)[i] = h;
  if (lo) {
    ushort4 l;
    l.x = f2bf(v.x - bf2f(h.x));
    l.y = f2bf(v.y - bf2f(h.y));
    l.z = f2bf(v.z - bf2f(h.z));
    l.w = f2bf(v.w - bf2f(h.w));
    reinterpret_cast<ushort4*>(lo)[i] = l;
  }
}

// ---------------------------------------------------------------------------
// Transpose + bf16: W [rows][cols] fp32 -> Thi [cols][rows] bf16 (hi only).
// ---------------------------------------------------------------------------
__global__ __launch_bounds__(256) void split_tr(
    const float* __restrict__ W, unsigned short* __restrict__ Thi,
    int rows, int cols)
{
  __shared__ float tile[32][33];
  const int c0 = blockIdx.x * 32, r0 = blockIdx.y * 32;
  const int tx = threadIdx.x & 31, ty = threadIdx.x >> 5;   // ty 0..7
  #pragma unroll
  for (int i = 0; i < 4; ++i)
    tile[ty + i * 8][tx] = W[(size_t)(r0 + ty + i * 8) * cols + c0 + tx];
  __syncthreads();
  #pragma unroll
  for (int i = 0; i < 4; ++i) {
    const int cr = ty + i * 8;
    Thi[(size_t)(c0 + cr) * rows + r0 + tx] = f2bf(tile[tx][cr]);
  }
}

// ---------------------------------------------------------------------------
// 2-product split-bf16 MFMA GEMM: C(16384xN) = (Ahi+Alo)(MxK) @ B + bias.
// BThi is [N][K] bf16, K=1024. BFOUT: emit hi/lo bf16, else fp32.
// 128x128 tile, BK=32, 4 waves of 64x64, global_load_lds(16B) staging.
// ---------------------------------------------------------------------------
template <bool BFOUT>
__global__ __launch_bounds__(256) void gemm_mfma2(
    const unsigned short* __restrict__ Ahi, const unsigned short* __restrict__ Alo,
    const unsigned short* __restrict__ BThi, const float* __restrict__ bias,
    float* __restrict__ Cf, unsigned short* __restrict__ Chi,
    unsigned short* __restrict__ Clo, int ldc)
{
  __shared__ unsigned short lds[3 * 4096];         // 24 KB: Ahi, Alo, Bhi
  unsigned short* sAhi = lds;
  unsigned short* sAlo = lds + 4096;
  unsigned short* sBhi = lds + 8192;

  const int tid  = threadIdx.x;
  const int lane = tid & 63;
  const int wid  = tid >> 6;
  const int m0 = blockIdx.y * 128;
  const int n0 = blockIdx.x * 128;

  const int srow  = lane >> 2;
  const int skseg = (lane & 3) << 3;
  const int col  = lane & 15;
  const int quad = lane >> 4;
  const int Rm = (wid >> 1) << 6;
  const int Rn = (wid & 1) << 6;

  f32x4 acc[4][4];
  #pragma unroll
  for (int i = 0; i < 4; ++i)
    #pragma unroll
    for (int j = 0; j < 4; ++j)
      acc[i][j] = (f32x4){0.f, 0.f, 0.f, 0.f};

  for (int k0 = 0; k0 < K_; k0 += 32) {
    #pragma unroll
    for (int r = 0; r < 2; ++r) {
      const int chunk = (r << 2) + wid;
      const int row = (chunk << 4) + srow;
      const int ldso = chunk << 9;
      const size_t ga = (size_t)(m0 + row) * K_ + k0 + skseg;
      const size_t gb = (size_t)(n0 + row) * K_ + k0 + skseg;
      GLOAD_LDS16(Ahi + ga, sAhi + ldso);
      GLOAD_LDS16(Alo + ga, sAlo + ldso);
      GLOAD_LDS16(BThi + gb, sBhi + ldso);
    }
    __syncthreads();

    bf16x8 ah[4], al[4], bh[4];
    #pragma unroll
    for (int t = 0; t < 4; ++t) {
      const int ao = ((Rm + (t << 4) + col) << 5) + (quad << 3);
      ah[t] = *reinterpret_cast<const bf16x8*>(sAhi + ao);
      al[t] = *reinterpret_cast<const bf16x8*>(sAlo + ao);
      const int bo = ((Rn + (t << 4) + col) << 5) + (quad << 3);
      bh[t] = *reinterpret_cast<const bf16x8*>(sBhi + bo);
    }
    #pragma unroll
    for (int i = 0; i < 4; ++i)
      #pragma unroll
      for (int j = 0; j < 4; ++j) {
        acc[i][j] = __builtin_amdgcn_mfma_f32_16x16x32_bf16(ah[i], bh[j], acc[i][j], 0, 0, 0);
        acc[i][j] = __builtin_amdgcn_mfma_f32_16x16x32_bf16(al[i], bh[j], acc[i][j], 0, 0, 0);
      }
    __syncthreads();
  }

  // C/D layout: col=lane&15, row=quad*4+reg (verified in-session).
  #pragma unroll
  for (int i = 0; i < 4; ++i) {
    const int rbase = m0 + Rm + (i << 4) + (quad << 2);
    #pragma unroll
    for (int j = 0; j < 4; ++j) {
      const int c = n0 + Rn + (j << 4) + col;
      const float bv = bias[c];
      #pragma unroll
      for (int rg = 0; rg < 4; ++rg) {
        const float v = acc[i][j][rg] + bv;
        const size_t o = (size_t)(rbase + rg) * ldc + c;
        if constexpr (BFOUT) {
          const unsigned short hv = f2bf(v);
          Chi[o] = hv;
          Clo[o] = f2bf(v - bf2f(hv));
        } else {
          Cf[o] = v;
        }
      }
    }
  }
}

// ---------------------------------------------------------------------------
// MFMA proj: part[(bh*TCH+tc)][kk=128][d=64] fp32 =
//   sum_{t in chunk of 512} E[h][kk][t] * (khi+klo)[b*T+t][h*64+d]
// grid (128 bh, TCH). A = E (single bf16, dense LDS pitch 72).
// B = k hi/lo, LDS-transposed to [d][t] pitch 72 via 4x4 register tiles.
// 2 products: Eh*kh + Eh*kl.
// ---------------------------------------------------------------------------
__global__ __launch_bounds__(256) void proj_mfma(
    const unsigned short* __restrict__ Eh,
    const unsigned short* __restrict__ khi, const unsigned short* __restrict__ klo,
    float* __restrict__ part)
{
  __shared__ unsigned short sE[KP * 72];           // 18.0 KB
  __shared__ unsigned short sKh[D_ * 72];          //  9.0 KB
  __shared__ unsigned short sKl[D_ * 72];          //  9.0 KB

  const int bh = blockIdx.x;
  const int tc = blockIdx.y;
  const int b = bh >> 4, h = bh & 15;
  const int tid = threadIdx.x;
  const int lane = tid & 63;
  const int w = tid >> 6;
  const int col = lane & 15;
  const int quad = lane >> 4;

  // staging indices
  const int tq = tid >> 4;            // 0..15 -> t-base tq*4
  const int dq = tid & 15;            // 0..15 -> d-base dq*4

  f32x4 acc[2][4];
  #pragma unroll
  for (int i = 0; i < 2; ++i)
    #pragma unroll
    for (int j = 0; j < 4; ++j) acc[i][j] = (f32x4){0.f, 0.f, 0.f, 0.f};

  for (int s = 0; s < 8; ++s) {
    const int t0 = tc * 512 + s * 64;
    // E tile [128 kk][64 t] -> sE pitch 72 (uint4 = 8 bf16 per op)
    #pragma unroll
    for (int l = 0; l < 4; ++l) {
      const int idx = l * 256 + tid;
      const int kk = idx >> 3, seg = idx & 7;
      *reinterpret_cast<uint4*>(sE + kk * 72 + seg * 8) =
          *reinterpret_cast<const uint4*>(
              Eh + (size_t)(h * KP + kk) * T_ + t0 + seg * 8);
    }
    // k tile [64 t][64 d] hi/lo -> transposed sK [d][t] pitch 72
    {
      const size_t gbase = (size_t)(b * T_ + t0 + tq * 4) * C_ + h * D_ + dq * 4;
      ushort4 rh[4], rl[4];
      #pragma unroll
      for (int r = 0; r < 4; ++r) {
        rh[r] = *reinterpret_cast<const ushort4*>(khi + gbase + (size_t)r * C_);
        rl[r] = *reinterpret_cast<const ushort4*>(klo + gbase + (size_t)r * C_);
      }
      #pragma unroll
      for (int c = 0; c < 4; ++c) {
        ushort4 th, tl;
        th.x = (&rh[0].x)[c]; th.y = (&rh[1].x)[c];
        th.z = (&rh[2].x)[c]; th.w = (&rh[3].x)[c];
        tl.x = (&rl[0].x)[c]; tl.y = (&rl[1].x)[c];
        tl.z = (&rl[2].x)[c]; tl.w = (&rl[3].x)[c];
        *reinterpret_cast<ushort4*>(sKh + (dq * 4 + c) * 72 + tq * 4) = th;
        *reinterpret_cast<ushort4*>(sKl + (dq * 4 + c) * 72 + tq * 4) = tl;
      }
    }
    __syncthreads();

    // wave w owns m-tiles {2w, 2w+1} (kk = wtile*16+col); n-tiles j (d)
    bf16x8 av[2][2];
    #pragma unroll
    for (int i = 0; i < 2; ++i)
      #pragma unroll
      for (int ks = 0; ks < 2; ++ks)
        av[i][ks] = *reinterpret_cast<const bf16x8*>(
            sE + ((w * 2 + i) * 16 + col) * 72 + ks * 32 + quad * 8);
    #pragma unroll
    for (int j = 0; j < 4; ++j)
      #pragma unroll
      for (int ks = 0; ks < 2; ++ks) {
        const int bo = (j * 16 + col) * 72 + ks * 32 + quad * 8;
        const bf16x8 bvh = *reinterpret_cast<const bf16x8*>(sKh + bo);
        const bf16x8 bvl = *reinterpret_cast<const bf16x8*>(sKl + bo);
        #pragma unroll
        for (int i = 0; i < 2; ++i) {
          acc[i][j] = __builtin_amdgcn_mfma_f32_16x16x32_bf16(av[i][ks], bvh, acc[i][j], 0, 0, 0);
          acc[i][j] = __builtin_amdgcn_mfma_f32_16x16x32_bf16(av[i][ks], bvl, acc[i][j], 0, 0, 0);
        }
      }
    __syncthreads();
  }

  float* op = part + ((size_t)bh * TCH + tc) * (KP * D_);
  #pragma unroll
  for (int i = 0; i < 2; ++i) {
    const int kkb = w * 32 + i * 16 + quad * 4;
    #pragma unroll
    for (int j = 0; j < 4; ++j) {
      const int d = j * 16 + col;
      #pragma unroll
      for (int rg = 0; rg < 4; ++rg)
        op[(kkb + rg) * D_ + d] = acc[i][j][rg];
    }
  }
}

// ---------------------------------------------------------------------------
// reduce_k: kprojh[bh][kk][d] (bf16) = sum_c part[bh][c][kk][d]
// ---------------------------------------------------------------------------
__global__ __launch_bounds__(256) void reduce_k(
    const float* __restrict__ part, unsigned short* __restrict__ kprojh)
{
  const int idx = blockIdx.x * 256 + threadIdx.x;   // over 128*8192
  const int bh = idx >> 13;
  const int i = idx & 8191;
  float s = 0.f;
  #pragma unroll
  for (int c = 0; c < TCH; ++c)
    s += part[((size_t)bh * TCH + c) * 8192 + i];
  kprojh[idx] = f2bf(s);
}

// ---------------------------------------------------------------------------
// reduce_v: vpT hi/lo [bh][d][kk] = transpose(sum_c part[bh][c][kk][d])
// ---------------------------------------------------------------------------
__global__ __launch_bounds__(256) void reduce_v(
    const float* __restrict__ part, unsigned short* __restrict__ vpTh,
    unsigned short* __restrict__ vpTl)
{
  __shared__ float sums[KP * 66];     // [kk][d] pitch 66
  const int bh = blockIdx.x;
  const int tid = threadIdx.x;
  #pragma unroll
  for (int j = 0; j < 32; ++j) {
    const int i = j * 256 + tid;      // kk = i>>6, d = i&63
    float s = 0.f;
    #pragma unroll
    for (int c = 0; c < TCH; ++c)
      s += part[((size_t)bh * TCH + c) * 8192 + i];
    sums[(i >> 6) * 66 + (i & 63)] = s;
  }
  __syncthreads();
  #pragma unroll
  for (int j = 0; j < 32; ++j) {
    const int i = j * 256 + tid;      // d = i>>7, kk = i&127
    const float s = sums[(i & 127) * 66 + (i >> 7)];
    const unsigned short h = f2bf(s);
    vpTh[(size_t)bh * 8192 + i] = h;
    vpTl[(size_t)bh * 8192 + i] = f2bf(s - bf2f(h));
  }
}

// ---------------------------------------------------------------------------
// MFMA attention core (R4-verified), q now read as hi/lo bf16.
// ---------------------------------------------------------------------------
__global__ __launch_bounds__(256) void attn_mfma(
    const unsigned short* __restrict__ qhi, const unsigned short* __restrict__ qlo,
    const unsigned short* __restrict__ kprojh,
    const unsigned short* __restrict__ vpTh, const unsigned short* __restrict__ vpTl,
    unsigned short* __restrict__ yhi, unsigned short* __restrict__ ylo)
{
  __shared__ __attribute__((aligned(16))) char lds[52480];
  unsigned short* Qh = (unsigned short*)(lds);
  unsigned short* Ql = (unsigned short*)(lds + 9216);
  unsigned short* Kp = (unsigned short*)(lds + 18432);
  unsigned short* Vh = (unsigned short*)(lds);
  unsigned short* Vl = (unsigned short*)(lds + 17408);
  unsigned short* Ps = (unsigned short*)(lds + 34816);
  float* atts = (float*)(lds + 52224);

  const int tid  = threadIdx.x;
  const int lane = tid & 63;
  const int w    = tid >> 6;
  const int col  = lane & 15;
  const int quad = lane >> 4;
  const int bh = blockIdx.x >> 5;
  const int tch = blockIdx.x & 31;
  const int b = bh >> 4, h = bh & 15;
  const int t0 = tch * 64;

  { // stage Q hi/lo (pitch 72) and Kp (pitch 72)
    const unsigned short* qgh = qhi + (size_t)(b * T_ + t0) * C_ + h * D_;
    const unsigned short* qgl = qlo + (size_t)(b * T_ + t0) * C_ + h * D_;
    #pragma unroll
    for (int l = 0; l < 4; ++l) {
      const int idx = l * 256 + tid;
      const int t = idx >> 4, dc = (idx & 15) << 2;
      *reinterpret_cast<ushort4*>(Qh + t * 72 + dc) =
          *reinterpret_cast<const ushort4*>(qgh + (size_t)t * C_ + dc);
      *reinterpret_cast<ushort4*>(Ql + t * 72 + dc) =
          *reinterpret_cast<const ushort4*>(qgl + (size_t)t * C_ + dc);
    }
    const unsigned short* kg = kprojh + (size_t)bh * 8192;
    #pragma unroll
    for (int l = 0; l < 8; ++l) {
      const int idx = l * 256 + tid;
      const int kk = idx >> 4, dc = (idx & 15) << 2;
      *reinterpret_cast<ushort4*>(Kp + kk * 72 + dc) =
          *reinterpret_cast<const ushort4*>(kg + kk * 64 + dc);
    }
  }
  __syncthreads();

  // S^T = Kp(A) @ Q^T(B): m=kk (8 tiles), n=t (wave strip), k=d (2 steps)
  f32x4 s[8];
  #pragma unroll
  for (int i = 0; i < 8; ++i) s[i] = (f32x4){0.f, 0.f, 0.f, 0.f};
  bf16x8 bqh[2], bql[2];
  #pragma unroll
  for (int ks = 0; ks < 2; ++ks) {
    const int off = (w * 16 + col) * 72 + ks * 32 + quad * 8;
    bqh[ks] = *reinterpret_cast<const bf16x8*>(Qh + off);
    bql[ks] = *reinterpret_cast<const bf16x8*>(Ql + off);
  }
  #pragma unroll
  for (int i = 0; i < 8; ++i)
    #pragma unroll
    for (int ks = 0; ks < 2; ++ks) {
      const bf16x8 a = *reinterpret_cast<const bf16x8*>(
          Kp + (i * 16 + col) * 72 + ks * 32 + quad * 8);
      s[i] = __builtin_amdgcn_mfma_f32_16x16x32_bf16(a, bqh[ks], s[i], 0, 0, 0);
      s[i] = __builtin_amdgcn_mfma_f32_16x16x32_bf16(a, bql[ks], s[i], 0, 0, 0);
    }

  // softmax over kk (t = w*16+col)
  float mx = -3.0e38f;
  #pragma unroll
  for (int i = 0; i < 8; ++i)
    #pragma unroll
    for (int rg = 0; rg < 4; ++rg) {
      s[i][rg] *= 0.125f;
      mx = fmaxf(mx, s[i][rg]);
    }
  mx = fmaxf(mx, __shfl_xor(mx, 16));
  mx = fmaxf(mx, __shfl_xor(mx, 32));
  float sum = 0.f;
  #pragma unroll
  for (int i = 0; i < 8; ++i)
    #pragma unroll
    for (int rg = 0; rg < 4; ++rg) {
      const float e = __expf(s[i][rg] - mx);
      s[i][rg] = e;
      sum += e;
    }
  sum += __shfl_xor(sum, 16);
  sum += __shfl_xor(sum, 32);
  const float inv = 1.f / sum;
  __syncthreads();

  { // stage Vp hi/lo (pitch 136)
    const unsigned short* vgh = vpTh + (size_t)bh * 8192;
    const unsigned short* vgl = vpTl + (size_t)bh * 8192;
    #pragma unroll
    for (int l = 0; l < 8; ++l) {
      const int idx = l * 256 + tid;
      const int d = idx >> 5, kc = (idx & 31) << 2;
      *reinterpret_cast<ushort4*>(Vh + d * 136 + kc) =
          *reinterpret_cast<const ushort4*>(vgh + d * 128 + kc);
      *reinterpret_cast<ushort4*>(Vl + d * 136 + kc) =
          *reinterpret_cast<const ushort4*>(vgl + d * 128 + kc);
    }
  }
  #pragma unroll
  for (int i = 0; i < 8; ++i) {
    ushort4 hp;
    hp.x = f2bf(s[i][0]); hp.y = f2bf(s[i][1]);
    hp.z = f2bf(s[i][2]); hp.w = f2bf(s[i][3]);
    *reinterpret_cast<ushort4*>(Ps + (w * 16 + col) * 136 + i * 16 + quad * 4) = hp;
  }
  if (quad == 0) atts[w * 16 + col] = inv;
  __syncthreads();

  // y = P(A) @ V(B): m=t (wave strip), n=d (4 tiles), k=kk (4 steps)
  f32x4 y[4];
  #pragma unroll
  for (int j = 0; j < 4; ++j) y[j] = (f32x4){0.f, 0.f, 0.f, 0.f};
  bf16x8 ap[4];
  #pragma unroll
  for (int ks = 0; ks < 4; ++ks)
    ap[ks] = *reinterpret_cast<const bf16x8*>(
        Ps + (w * 16 + col) * 136 + ks * 32 + quad * 8);
  #pragma unroll
  for (int j = 0; j < 4; ++j)
    #pragma unroll
    for (int ks = 0; ks < 4; ++ks) {
      const int off = (j * 16 + col) * 136 + ks * 32 + quad * 8;
      const bf16x8 bvh = *reinterpret_cast<const bf16x8*>(Vh + off);
      const bf16x8 bvl = *reinterpret_cast<const bf16x8*>(Vl + off);
      y[j] = __builtin_amdgcn_mfma_f32_16x16x32_bf16(ap[ks], bvh, y[j], 0, 0, 0);
      y[j] = __builtin_amdgcn_mfma_f32_16x16x32_bf16(ap[ks], bvl, y[j], 0, 0, 0);
    }

  const f32x4 inv4 = *reinterpret_cast<const f32x4*>(atts + w * 16 + quad * 4);
  #pragma unroll
  for (int j = 0; j < 4; ++j)
    #pragma unroll
    for (int rg = 0; rg < 4; ++rg) {
      const int t = t0 + w * 16 + quad * 4 + rg;
      const int d = j * 16 + col;
      const float val = y[j][rg] * inv4[rg];
      const size_t o = (size_t)(b * T_ + t) * C_ + h * D_ + d;
      const unsigned short hv = f2bf(val);
      yhi[o] = hv;
      ylo[o] = f2bf(val - bf2f(hv));
    }
}

// ---------------------------------------------------------------------------
extern "C" void kernel_launch(void* const* d_in, const int* in_sizes, int n_in,
                              void* d_out, int out_size, void* d_ws, size_t ws_size,
                              hipStream_t stream) {
  (void)in_sizes; (void)n_in; (void)out_size; (void)ws_size;
  const float* x      = (const float*)d_in[0];
  const float* W_attn = (const float*)d_in[1];
  const float* b_attn = (const float*)d_in[2];
  const float* W_proj = (const float*)d_in[3];
  const float* b_proj = (const float*)d_in[4];
  const float* E      = (const float*)d_in[5];
  const float* F      = (const float*)d_in[6];
  float* out = (float*)d_out;

  // ws regions, 182.5 MB peak (R3-proven size):
  unsigned short* xhi   = (unsigned short*)d_ws;
  unsigned short* xlo   = xhi + (size_t)M_ * C_;        // 33.55 MB each
  unsigned short* kvqh  = xlo + (size_t)M_ * C_;        // shared k/v/q hi
  unsigned short* kvql  = kvqh + (size_t)M_ * C_;       // shared k/v/q lo
  unsigned short* WaThi = kvql + (size_t)M_ * C_;       // [3072][1024] 6.29 MB
  unsigned short* WpT   = WaThi + (size_t)C3 * C_;      // [1024][1024] 2.10 MB
  unsigned short* Ehi   = WpT + (size_t)C_ * C_;        // [16][128][2048] 8.39 MB
  unsigned short* Fhi   = Ehi + (size_t)H_ * KP * T_;   // 8.39 MB
  float* part = (float*)(Fhi + (size_t)H_ * KP * T_);   // 128*4*8192*4 = 16.78 MB
  unsigned short* kprojh = (unsigned short*)(part + (size_t)B_ * H_ * TCH * KP * D_);
  unsigned short* vpTh   = kprojh + (size_t)B_ * H_ * KP * D_;   // 2.10 MB each
  unsigned short* vpTl   = vpTh + (size_t)B_ * H_ * KP * D_;
  unsigned short* yhi = xhi;                            // x dead after q-GEMM
  unsigned short* ylo = xlo;

  // 0) precision splits
  split_rm<<<(M_ * C_ / 4 + 255) / 256, 256, 0, stream>>>(x, xhi, xlo, M_ * C_ / 4);
  split_rm<<<(H_ * KP * T_ / 4 + 255) / 256, 256, 0, stream>>>(E, Ehi, nullptr, H_ * KP * T_ / 4);
  split_rm<<<(H_ * KP * T_ / 4 + 255) / 256, 256, 0, stream>>>(F, Fhi, nullptr, H_ * KP * T_ / 4);
  split_tr<<<dim3(C3 / 32, C_ / 32), 256, 0, stream>>>(W_attn, WaThi, C_, C3);
  split_tr<<<dim3(C_ / 32, C_ / 32), 256, 0, stream>>>(W_proj, WpT, C_, C_);

  // 1) k = x @ Wk + bk (bf16 hi/lo); kproj = E @ k (MFMA partials + reduce)
  gemm_mfma2<true><<<dim3(C_ / 128, M_ / 128), 256, 0, stream>>>(
      xhi, xlo, WaThi + (size_t)C_ * K_, b_attn + C_, nullptr, kvqh, kvql, C_);
  proj_mfma<<<dim3(B_ * H_, TCH), 256, 0, stream>>>(Ehi, kvqh, kvql, part);
  reduce_k<<<(B_ * H_ * KP * D_) / 256, 256, 0, stream>>>(part, kprojh);

  // 2) v = x @ Wv + bv; vpT hi/lo = transpose(F @ v)
  gemm_mfma2<true><<<dim3(C_ / 128, M_ / 128), 256, 0, stream>>>(
      xhi, xlo, WaThi + (size_t)2 * C_ * K_, b_attn + 2 * C_, nullptr, kvqh, kvql, C_);
  proj_mfma<<<dim3(B_ * H_, TCH), 256, 0, stream>>>(Fhi, kvqh, kvql, part);
  reduce_v<<<B_ * H_, 256, 0, stream>>>(part, vpTh, vpTl);

  // 3) q = x @ Wq + bq
  gemm_mfma2<true><<<dim3(C_ / 128, M_ / 128), 256, 0, stream>>>(
      xhi, xlo, WaThi, b_attn, nullptr, kvqh, kvql, C_);

  // 4) MFMA attention -> y hi/lo (overwrites x splits)
  attn_mfma<<<B_ * H_ * (T_ / 64), 256, 0, stream>>>(
      kvqh, kvql, kprojh, vpTh, vpTl, yhi, ylo);

  // 5) out = y @ W_proj + b_proj (fp32 epilogue)
  gemm_mfma2<false><<<dim3(C_ / 128, M_ / 128), 256, 0, stream>>>(
      yhi, ylo, WpT, b_proj, out, nullptr, nullptr, C_);
}

// Round 6
// 409.477 us; speedup vs baseline: 4.7685x; 1.5063x over previous
//
#include <hip/hip_runtime.h>
#include <math.h>

// LinformerAttention on MI355X — Round 6: single-bf16 everywhere (1-product
// MFMA throughout; the GEMM K-loop is exactly the m97 structure). Fused
// qkv GEMM (N=3072). B=8 T=2048 C=1024 H=16 D=64 Kproj=128. ws ~180 MB.

constexpr int B_ = 8, T_ = 2048, C_ = 1024, H_ = 16, D_ = 64, KP = 128;
constexpr int M_ = B_ * T_;            // 16384
constexpr int C3 = 3 * C_;             // 3072
constexpr int K_ = C_;                 // GEMM K = 1024
constexpr int TCH = 4;                 // proj t-chunks of 512

typedef __attribute__((ext_vector_type(8))) short bf16x8;   // 8 bf16 = 4 VGPR
typedef __attribute__((ext_vector_type(4))) float f32x4;

__device__ __forceinline__ unsigned short f2bf(float f) {
  unsigned u = __builtin_bit_cast(unsigned, f);
  u += 0x7FFFu + ((u >> 16) & 1u);     // round-to-nearest-even
  return (unsigned short)(u >> 16);
}
__device__ __forceinline__ float bf2f(unsigned short h) {
  unsigned u = ((unsigned)h) << 16;
  return __builtin_bit_cast(float, u);
}

#define GLOAD_LDS16(gptr, lptr)                                                \
  __builtin_amdgcn_global_load_lds(                                            \
      (const __attribute__((address_space(1))) void*)(gptr),                   \
      (__attribute__((address_space(3))) void*)(lptr), 16, 0, 0)

// ---------------------------------------------------------------------------
// fp32 -> bf16 (hi) cast, row-major. n4 = n/4.
// ---------------------------------------------------------------------------
__global__ __launch_bounds__(256) void cast_bf16(
    const float* __restrict__ in, unsigned short* __restrict__ hi, int n4)
{
  int i = blockIdx.x * 256 + threadIdx.x;
  if (i >= n4) return;
  const float4 v = reinterpret_cast<const float4*>(in)[i];
  ushort4 h;
  h.x = f2bf(v.x); h.y = f2bf(v.y); h.z = f2bf(v.z); h.w = f2bf(v.w);
  reinterpret_cast<ushort4*>(hi)[i] = h;
}

// ---------------------------------------------------------------------------
// Transpose + bf16: W [rows][cols] fp32 -> T [cols][rows] bf16.
// ---------------------------------------------------------------------------
__global__ __launch_bounds__(256) void cast_tr(
    const float* __restrict__ W, unsigned short* __restrict__ Tb,
    int rows, int cols)
{
  __shared__ float tile[32][33];
  const int c0 = blockIdx.x * 32, r0 = blockIdx.y * 32;
  const int tx = threadIdx.x & 31, ty = threadIdx.x >> 5;   // ty 0..7
  #pragma unroll
  for (int i = 0; i < 4; ++i)
    tile[ty + i * 8][tx] = W[(size_t)(r0 + ty + i * 8) * cols + c0 + tx];
  __syncthreads();
  #pragma unroll
  for (int i = 0; i < 4; ++i) {
    const int cr = ty + i * 8;
    Tb[(size_t)(c0 + cr) * rows + r0 + tx] = f2bf(tile[tx][cr]);
  }
}

// ---------------------------------------------------------------------------
// Single-bf16 MFMA GEMM (m97 structure): C(16384xN) = A(MxK) @ B + bias.
// BT is [N][K] bf16, K=1024. BFOUT: emit bf16, else fp32.
// 128x128 tile, BK=32, 4 waves of 64x64, global_load_lds(16B) staging,
// 16 MFMA + 8 ds_read_b128 per K-step.
// ---------------------------------------------------------------------------
template <bool BFOUT>
__global__ __launch_bounds__(256) void gemm_mfma1(
    const unsigned short* __restrict__ A, const unsigned short* __restrict__ BT,
    const float* __restrict__ bias, float* __restrict__ Cf,
    unsigned short* __restrict__ Cb, int ldc)
{
  __shared__ unsigned short lds[2 * 4096];         // 16 KB: A, B tiles (128x32)
  unsigned short* sA = lds;
  unsigned short* sB = lds + 4096;

  const int tid  = threadIdx.x;
  const int lane = tid & 63;
  const int wid  = tid >> 6;
  const int m0 = blockIdx.y * 128;
  const int n0 = blockIdx.x * 128;

  const int srow  = lane >> 2;                     // staging row in 16-chunk
  const int skseg = (lane & 3) << 3;               // staging k sub-offset
  const int col  = lane & 15;
  const int quad = lane >> 4;
  const int Rm = (wid >> 1) << 6;
  const int Rn = (wid & 1) << 6;

  f32x4 acc[4][4];
  #pragma unroll
  for (int i = 0; i < 4; ++i)
    #pragma unroll
    for (int j = 0; j < 4; ++j)
      acc[i][j] = (f32x4){0.f, 0.f, 0.f, 0.f};

  for (int k0 = 0; k0 < K_; k0 += 32) {
    #pragma unroll
    for (int r = 0; r < 2; ++r) {
      const int chunk = (r << 2) + wid;            // 0..7, wave-uniform
      const int row = (chunk << 4) + srow;
      const int ldso = chunk << 9;
      GLOAD_LDS16(A + (size_t)(m0 + row) * K_ + k0 + skseg, sA + ldso);
      GLOAD_LDS16(BT + (size_t)(n0 + row) * K_ + k0 + skseg, sB + ldso);
    }
    __syncthreads();

    bf16x8 a[4], b[4];
    #pragma unroll
    for (int t = 0; t < 4; ++t) {
      a[t] = *reinterpret_cast<const bf16x8*>(
          sA + ((Rm + (t << 4) + col) << 5) + (quad << 3));
      b[t] = *reinterpret_cast<const bf16x8*>(
          sB + ((Rn + (t << 4) + col) << 5) + (quad << 3));
    }
    #pragma unroll
    for (int i = 0; i < 4; ++i)
      #pragma unroll
      for (int j = 0; j < 4; ++j)
        acc[i][j] = __builtin_amdgcn_mfma_f32_16x16x32_bf16(a[i], b[j], acc[i][j], 0, 0, 0);
    __syncthreads();
  }

  // C/D layout: col=lane&15, row=quad*4+reg (verified in-session R3..R5).
  #pragma unroll
  for (int i = 0; i < 4; ++i) {
    const int rbase = m0 + Rm + (i << 4) + (quad << 2);
    #pragma unroll
    for (int j = 0; j < 4; ++j) {
      const int c = n0 + Rn + (j << 4) + col;
      const float bv = bias[c];
      #pragma unroll
      for (int rg = 0; rg < 4; ++rg) {
        const float v = acc[i][j][rg] + bv;
        const size_t o = (size_t)(rbase + rg) * ldc + c;
        if constexpr (BFOUT) Cb[o] = f2bf(v);
        else Cf[o] = v;
      }
    }
  }
}

// ---------------------------------------------------------------------------
// MFMA proj (1-product): part[(bh*TCH+tc)][kk=128][d=64] fp32 =
//   sum_{t in 512-chunk} E[h][kk][t] * k[b*T+t][h*64+d]
// A = E bf16 (dense pitch 72). B = k bf16 [M][ldk], LDS-transposed to
// [d][t] pitch 72 via 4x4 register tiles. grid (128 bh, TCH).
// ---------------------------------------------------------------------------
__global__ __launch_bounds__(256) void proj_mfma(
    const unsigned short* __restrict__ Eh, const unsigned short* __restrict__ kb,
    int ldk, float* __restrict__ part)
{
  __shared__ unsigned short sE[KP * 72];           // 18.0 KB
  __shared__ unsigned short sK[D_ * 72];           //  9.0 KB

  const int bh = blockIdx.x;
  const int tc = blockIdx.y;
  const int b = bh >> 4, h = bh & 15;
  const int tid = threadIdx.x;
  const int lane = tid & 63;
  const int w = tid >> 6;
  const int col = lane & 15;
  const int quad = lane >> 4;
  const int tq = tid >> 4;            // 0..15 -> t-base tq*4
  const int dq = tid & 15;            // 0..15 -> d-base dq*4

  f32x4 acc[2][4];
  #pragma unroll
  for (int i = 0; i < 2; ++i)
    #pragma unroll
    for (int j = 0; j < 4; ++j) acc[i][j] = (f32x4){0.f, 0.f, 0.f, 0.f};

  for (int s = 0; s < 8; ++s) {
    const int t0 = tc * 512 + s * 64;
    #pragma unroll
    for (int l = 0; l < 4; ++l) {
      const int idx = l * 256 + tid;
      const int kk = idx >> 3, seg = idx & 7;
      *reinterpret_cast<uint4*>(sE + kk * 72 + seg * 8) =
          *reinterpret_cast<const uint4*>(
              Eh + (size_t)(h * KP + kk) * T_ + t0 + seg * 8);
    }
    {
      const size_t gbase = (size_t)(b * T_ + t0 + tq * 4) * ldk + h * D_ + dq * 4;
      ushort4 r[4];
      #pragma unroll
      for (int rr = 0; rr < 4; ++rr)
        r[rr] = *reinterpret_cast<const ushort4*>(kb + gbase + (size_t)rr * ldk);
      #pragma unroll
      for (int c = 0; c < 4; ++c) {
        ushort4 t;
        t.x = (&r[0].x)[c]; t.y = (&r[1].x)[c];
        t.z = (&r[2].x)[c]; t.w = (&r[3].x)[c];
        *reinterpret_cast<ushort4*>(sK + (dq * 4 + c) * 72 + tq * 4) = t;
      }
    }
    __syncthreads();

    bf16x8 av[2][2];
    #pragma unroll
    for (int i = 0; i < 2; ++i)
      #pragma unroll
      for (int ks = 0; ks < 2; ++ks)
        av[i][ks] = *reinterpret_cast<const bf16x8*>(
            sE + ((w * 2 + i) * 16 + col) * 72 + ks * 32 + quad * 8);
    #pragma unroll
    for (int j = 0; j < 4; ++j)
      #pragma unroll
      for (int ks = 0; ks < 2; ++ks) {
        const bf16x8 bv = *reinterpret_cast<const bf16x8*>(
            sK + (j * 16 + col) * 72 + ks * 32 + quad * 8);
        #pragma unroll
        for (int i = 0; i < 2; ++i)
          acc[i][j] = __builtin_amdgcn_mfma_f32_16x16x32_bf16(av[i][ks], bv, acc[i][j], 0, 0, 0);
      }
    __syncthreads();
  }

  float* op = part + ((size_t)bh * TCH + tc) * (KP * D_);
  #pragma unroll
  for (int i = 0; i < 2; ++i) {
    const int kkb = w * 32 + i * 16 + quad * 4;
    #pragma unroll
    for (int j = 0; j < 4; ++j) {
      const int d = j * 16 + col;
      #pragma unroll
      for (int rg = 0; rg < 4; ++rg)
        op[(kkb + rg) * D_ + d] = acc[i][j][rg];
    }
  }
}

// ---------------------------------------------------------------------------
// reduce_k: kprojh[bh][kk][d] (bf16) = sum_c part[bh][c][kk][d]
// ---------------------------------------------------------------------------
__global__ __launch_bounds__(256) void reduce_k(
    const float* __restrict__ part, unsigned short* __restrict__ kprojh)
{
  const int idx = blockIdx.x * 256 + threadIdx.x;   // over 128*8192
  const int bh = idx >> 13;
  const int i = idx & 8191;
  float s = 0.f;
  #pragma unroll
  for (int c = 0; c < TCH; ++c)
    s += part[((size_t)bh * TCH + c) * 8192 + i];
  kprojh[idx] = f2bf(s);
}

// ---------------------------------------------------------------------------
// reduce_v: vpT [bh][d][kk] bf16 = transpose(sum_c part[bh][c][kk][d])
// ---------------------------------------------------------------------------
__global__ __launch_bounds__(256) void reduce_v(
    const float* __restrict__ part, unsigned short* __restrict__ vpTh)
{
  __shared__ float sums[KP * 66];     // [kk][d] pitch 66
  const int bh = blockIdx.x;
  const int tid = threadIdx.x;
  #pragma unroll
  for (int j = 0; j < 32; ++j) {
    const int i = j * 256 + tid;      // kk = i>>6, d = i&63
    float s = 0.f;
    #pragma unroll
    for (int c = 0; c < TCH; ++c)
      s += part[((size_t)bh * TCH + c) * 8192 + i];
    sums[(i >> 6) * 66 + (i & 63)] = s;
  }
  __syncthreads();
  #pragma unroll
  for (int j = 0; j < 32; ++j) {
    const int i = j * 256 + tid;      // d = i>>7, kk = i&127
    vpTh[(size_t)bh * 8192 + i] = f2bf(sums[(i & 127) * 66 + (i >> 7)]);
  }
}

// ---------------------------------------------------------------------------
// MFMA attention (1-product): q bf16 from qkv[.., 0..C) (ld C3),
// kproj bf16 [kk][d], vpT bf16 [d][kk]; y bf16 out [M][C].
// ---------------------------------------------------------------------------
__global__ __launch_bounds__(256) void attn_mfma(
    const unsigned short* __restrict__ qkv, const unsigned short* __restrict__ kprojh,
    const unsigned short* __restrict__ vpTh, unsigned short* __restrict__ yh)
{
  // LDS union (35072 B): A: Qh@0(9216) Kp@9216(18432) end 27648
  //                      B: Vh@0(17408) Ps@17408(17408) atts@34816(256)
  __shared__ __attribute__((aligned(16))) char lds[35072];
  unsigned short* Qh = (unsigned short*)(lds);
  unsigned short* Kp = (unsigned short*)(lds + 9216);
  unsigned short* Vh = (unsigned short*)(lds);
  unsigned short* Ps = (unsigned short*)(lds + 17408);
  float* atts = (float*)(lds + 34816);

  const int tid  = threadIdx.x;
  const int lane = tid & 63;
  const int w    = tid >> 6;
  const int col  = lane & 15;
  const int quad = lane >> 4;
  const int bh = blockIdx.x >> 5;
  const int tch = blockIdx.x & 31;
  const int b = bh >> 4, h = bh & 15;
  const int t0 = tch * 64;

  { // stage Q (pitch 72) and Kp (pitch 72)
    const unsigned short* qg = qkv + (size_t)(b * T_ + t0) * C3 + h * D_;
    #pragma unroll
    for (int l = 0; l < 4; ++l) {
      const int idx = l * 256 + tid;
      const int t = idx >> 4, dc = (idx & 15) << 2;
      *reinterpret_cast<ushort4*>(Qh + t * 72 + dc) =
          *reinterpret_cast<const ushort4*>(qg + (size_t)t * C3 + dc);
    }
    const unsigned short* kg = kprojh + (size_t)bh * 8192;
    #pragma unroll
    for (int l = 0; l < 8; ++l) {
      const int idx = l * 256 + tid;
      const int kk = idx >> 4, dc = (idx & 15) << 2;
      *reinterpret_cast<ushort4*>(Kp + kk * 72 + dc) =
          *reinterpret_cast<const ushort4*>(kg + kk * 64 + dc);
    }
  }
  __syncthreads();

  // S^T = Kp(A) @ Q^T(B): m=kk (8 tiles), n=t (wave strip), k=d (2 steps)
  f32x4 s[8];
  #pragma unroll
  for (int i = 0; i < 8; ++i) s[i] = (f32x4){0.f, 0.f, 0.f, 0.f};
  bf16x8 bq[2];
  #pragma unroll
  for (int ks = 0; ks < 2; ++ks)
    bq[ks] = *reinterpret_cast<const bf16x8*>(
        Qh + (w * 16 + col) * 72 + ks * 32 + quad * 8);
  #pragma unroll
  for (int i = 0; i < 8; ++i)
    #pragma unroll
    for (int ks = 0; ks < 2; ++ks) {
      const bf16x8 a = *reinterpret_cast<const bf16x8*>(
          Kp + (i * 16 + col) * 72 + ks * 32 + quad * 8);
      s[i] = __builtin_amdgcn_mfma_f32_16x16x32_bf16(a, bq[ks], s[i], 0, 0, 0);
    }

  // softmax over kk (t = w*16+col)
  float mx = -3.0e38f;
  #pragma unroll
  for (int i = 0; i < 8; ++i)
    #pragma unroll
    for (int rg = 0; rg < 4; ++rg) {
      s[i][rg] *= 0.125f;
      mx = fmaxf(mx, s[i][rg]);
    }
  mx = fmaxf(mx, __shfl_xor(mx, 16));
  mx = fmaxf(mx, __shfl_xor(mx, 32));
  float sum = 0.f;
  #pragma unroll
  for (int i = 0; i < 8; ++i)
    #pragma unroll
    for (int rg = 0; rg < 4; ++rg) {
      const float e = __expf(s[i][rg] - mx);
      s[i][rg] = e;
      sum += e;
    }
  sum += __shfl_xor(sum, 16);
  sum += __shfl_xor(sum, 32);
  const float inv = 1.f / sum;
  __syncthreads();

  { // stage Vp (pitch 136)
    const unsigned short* vg = vpTh + (size_t)bh * 8192;
    #pragma unroll
    for (int l = 0; l < 8; ++l) {
      const int idx = l * 256 + tid;
      const int d = idx >> 5, kc = (idx & 31) << 2;
      *reinterpret_cast<ushort4*>(Vh + d * 136 + kc) =
          *reinterpret_cast<const ushort4*>(vg + d * 128 + kc);
    }
  }
  #pragma unroll
  for (int i = 0; i < 8; ++i) {
    ushort4 hp;
    hp.x = f2bf(s[i][0]); hp.y = f2bf(s[i][1]);
    hp.z = f2bf(s[i][2]); hp.w = f2bf(s[i][3]);
    *reinterpret_cast<ushort4*>(Ps + (w * 16 + col) * 136 + i * 16 + quad * 4) = hp;
  }
  if (quad == 0) atts[w * 16 + col] = inv;
  __syncthreads();

  // y = P(A) @ V(B): m=t (wave strip), n=d (4 tiles), k=kk (4 steps)
  f32x4 y[4];
  #pragma unroll
  for (int j = 0; j < 4; ++j) y[j] = (f32x4){0.f, 0.f, 0.f, 0.f};
  bf16x8 ap[4];
  #pragma unroll
  for (int ks = 0; ks < 4; ++ks)
    ap[ks] = *reinterpret_cast<const bf16x8*>(
        Ps + (w * 16 + col) * 136 + ks * 32 + quad * 8);
  #pragma unroll
  for (int j = 0; j < 4; ++j)
    #pragma unroll
    for (int ks = 0; ks < 4; ++ks) {
      const bf16x8 bv = *reinterpret_cast<const bf16x8*>(
          Vh + (j * 16 + col) * 136 + ks * 32 + quad * 8);
      y[j] = __builtin_amdgcn_mfma_f32_16x16x32_bf16(ap[ks], bv, y[j], 0, 0, 0);
    }

  const f32x4 inv4 = *reinterpret_cast<const f32x4*>(atts + w * 16 + quad * 4);
  #pragma unroll
  for (int j = 0; j < 4; ++j)
    #pragma unroll
    for (int rg = 0; rg < 4; ++rg) {
      const int t = t0 + w * 16 + quad * 4 + rg;
      const int d = j * 16 + col;
      yh[(size_t)(b * T_ + t) * C_ + h * D_ + d] = f2bf(y[j][rg] * inv4[rg]);
    }
}

// ---------------------------------------------------------------------------
extern "C" void kernel_launch(void* const* d_in, const int* in_sizes, int n_in,
                              void* d_out, int out_size, void* d_ws, size_t ws_size,
                              hipStream_t stream) {
  (void)in_sizes; (void)n_in; (void)out_size; (void)ws_size;
  const float* x      = (const float*)d_in[0];
  const float* W_attn = (const float*)d_in[1];
  const float* b_attn = (const float*)d_in[2];
  const float* W_proj = (const float*)d_in[3];
  const float* b_proj = (const float*)d_in[4];
  const float* E      = (const float*)d_in[5];
  const float* F      = (const float*)d_in[6];
  float* out = (float*)d_out;

  // ws regions, ~180.4 MB peak (182.5 proved safe in R5):
  unsigned short* xh   = (unsigned short*)d_ws;          // [M][C]  33.55 MB
  unsigned short* qkvh = xh + (size_t)M_ * C_;           // [M][3C] 100.66 MB
  unsigned short* WaT  = qkvh + (size_t)M_ * C3;         // [3072][1024] 6.29 MB
  unsigned short* WpT  = WaT + (size_t)C3 * C_;          // [1024][1024] 2.10 MB
  unsigned short* Eh   = WpT + (size_t)C_ * C_;          // 8.39 MB
  unsigned short* Fh   = Eh + (size_t)H_ * KP * T_;      // 8.39 MB
  float* part = (float*)(Fh + (size_t)H_ * KP * T_);     // 16.78 MB
  unsigned short* kprojh = (unsigned short*)(part + (size_t)B_ * H_ * TCH * KP * D_);
  unsigned short* vpTh   = kprojh + (size_t)B_ * H_ * KP * D_;   // 2.10 MB each
  unsigned short* yh = xh;                               // x dead after qkv GEMM

  // 0) casts / transposes
  cast_bf16<<<(M_ * C_ / 4 + 255) / 256, 256, 0, stream>>>(x, xh, M_ * C_ / 4);
  cast_bf16<<<(H_ * KP * T_ / 4 + 255) / 256, 256, 0, stream>>>(E, Eh, H_ * KP * T_ / 4);
  cast_bf16<<<(H_ * KP * T_ / 4 + 255) / 256, 256, 0, stream>>>(F, Fh, H_ * KP * T_ / 4);
  cast_tr<<<dim3(C3 / 32, C_ / 32), 256, 0, stream>>>(W_attn, WaT, C_, C3);
  cast_tr<<<dim3(C_ / 32, C_ / 32), 256, 0, stream>>>(W_proj, WpT, C_, C_);

  // 1) qkv = x @ W_attn + b_attn  (fused, N=3072, bf16 out)
  gemm_mfma1<true><<<dim3(C3 / 128, M_ / 128), 256, 0, stream>>>(
      xh, WaT, b_attn, nullptr, qkvh, C3);

  // 2) kproj = E @ k  (k = qkv cols [C,2C))
  proj_mfma<<<dim3(B_ * H_, TCH), 256, 0, stream>>>(Eh, qkvh + C_, C3, part);
  reduce_k<<<(B_ * H_ * KP * D_) / 256, 256, 0, stream>>>(part, kprojh);

  // 3) vpT = transpose(F @ v)  (v = qkv cols [2C,3C))
  proj_mfma<<<dim3(B_ * H_, TCH), 256, 0, stream>>>(Fh, qkvh + 2 * C_, C3, part);
  reduce_v<<<B_ * H_, 256, 0, stream>>>(part, vpTh);

  // 4) MFMA attention -> y bf16 (overwrites x region)
  attn_mfma<<<B_ * H_ * (T_ / 64), 256, 0, stream>>>(qkvh, kprojh, vpTh, yh);

  // 5) out = y @ W_proj + b_proj (fp32 out)
  gemm_mfma1<false><<<dim3(C_ / 128, M_ / 128), 256, 0, stream>>>(
      yh, WpT, b_proj, out, nullptr, C_);
}